// Round 2
// baseline (695.783 us; speedup 1.0000x reference)
//
#include <hip/hip_runtime.h>
#include <math.h>

namespace {
constexpr int B   = 4;
constexpr int CIN = 128;   // high channels
constexpr int CO  = 64;    // up / aligned channels
constexpr int HF  = 64;    // high H=W
constexpr int HO  = 128;   // up/out H=W
constexpr int HW  = HO * HO;   // 16384
constexpr int NOFF = 27;   // 18 offset + 9 mask channels

// workspace layout (float offsets)
constexpr size_t UPT   = 0;                          // [B][HO][HO][CO]  NHWC up
constexpr size_t FOO   = UPT  + (size_t)B * HW * CO; // [B][27][HO][HO]  offsets+mask
constexpr size_t WTUP  = FOO  + (size_t)B * NOFF * HW; // [3][3][CIN][CO]
constexpr size_t WTOFF = WTUP + (size_t)9 * CIN * CO;  // [CIN][9][32]
constexpr size_t WTAL  = WTOFF + (size_t)CIN * 9 * 32; // [9][CO][CO]
}

// ---------------- weight repack: put output channel innermost (uniform s_load) ----
__global__ void k_repack(const float* __restrict__ wup, const float* __restrict__ woff,
                         const float* __restrict__ wal, float* __restrict__ ws) {
  int i = blockIdx.x * 256 + threadIdx.x;
  if (i < 9 * CIN * CO) {                 // src w_up[c][o][ry][rx] -> [ry][rx][c][o]
    int rx = i % 3; int t = i / 3; int ry = t % 3; t /= 3;
    int o = t % CO; int c = t / CO;
    ws[WTUP + ((size_t)(ry * 3 + rx) * CIN + c) * CO + o] = wup[i];
  }
  if (i < CIN * 9 * 32) {                 // dst [c][kt][32] from w_off[oc][c][ky][kx]
    int oc = i & 31; int t = i >> 5; int kt = t % 9; int c = t / 9;
    float v = 0.f;
    if (oc < NOFF) v = woff[((size_t)(oc * CIN + c) * 3 + kt / 3) * 3 + (kt % 3)];
    ws[WTOFF + i] = v;
  }
  if (i < 9 * CO * CO) {                  // dst [k][c][o] from w_align[o][c][k]
    int o = i & 63; int t = i >> 6; int c = t & 63; int k = t >> 6;
    ws[WTAL + i] = wal[((size_t)o * CO + c) * 9 + k];
  }
}

// ---------------- K1: transposed conv (parity-decomposed), NHWC output -----------
// grid (16 tiles, 4 parity, B*4 o-quarters), block 256 = 16x16 same-parity pixels
__global__ __launch_bounds__(256) void k_up(const float* __restrict__ high,
                                            const float* __restrict__ bup,
                                            float* __restrict__ ws) {
  __shared__ float lds[8][17][17];
  const float* wt = ws + WTUP;
  float* upT = ws + UPT;

  const int t  = threadIdx.x;
  const int p  = blockIdx.y; const int py = p >> 1, px = p & 1;
  const int b  = blockIdx.z >> 2; const int oh = (blockIdx.z & 3) * 16;
  const int tY = (blockIdx.x >> 2) * 32, tX = (blockIdx.x & 3) * 32;
  const int sy = t >> 4, sx = t & 15;
  const int iyB = tY >> 1, ixB = tX >> 1;

  float acc[16];
#pragma unroll
  for (int j = 0; j < 16; j++) acc[j] = 0.f;

  int relY[2], ryA[2], nty, relX[2], rxA[2], ntx;
  if (py == 0) { nty = 1; relY[0] = sy;     ryA[0] = 1; relY[1] = 0;      ryA[1] = 0; }
  else         { nty = 2; relY[0] = sy;     ryA[0] = 2; relY[1] = sy + 1; ryA[1] = 0; }
  if (px == 0) { ntx = 1; relX[0] = sx;     rxA[0] = 1; relX[1] = 0;      rxA[1] = 0; }
  else         { ntx = 2; relX[0] = sx;     rxA[0] = 2; relX[1] = sx + 1; rxA[1] = 0; }

  for (int c0 = 0; c0 < CIN; c0 += 8) {
    __syncthreads();
    for (int i = t; i < 8 * 289; i += 256) {
      int cl = i / 289; int rem = i - cl * 289; int r = rem / 17; int cc = rem - r * 17;
      int iy = iyB + r, ix = ixB + cc;
      float v = 0.f;
      if (iy < HF && ix < HF) v = high[((size_t)(b * CIN + c0 + cl) * HF + iy) * HF + ix];
      lds[cl][r][cc] = v;
    }
    __syncthreads();
#pragma unroll
    for (int cl = 0; cl < 8; cl++) {
      int c = c0 + cl;
#pragma unroll
      for (int ti = 0; ti < 2; ti++) {
        if (ti < nty) {
#pragma unroll
          for (int tj = 0; tj < 2; tj++) {
            if (tj < ntx) {
              float v = lds[cl][relY[ti]][relX[tj]];
              const float4* w4 =
                  (const float4*)(wt + ((size_t)(ryA[ti] * 3 + rxA[tj]) * CIN + c) * CO + oh);
#pragma unroll
              for (int j = 0; j < 4; j++) {
                float4 w = w4[j];
                acc[4 * j + 0] = fmaf(v, w.x, acc[4 * j + 0]);
                acc[4 * j + 1] = fmaf(v, w.y, acc[4 * j + 1]);
                acc[4 * j + 2] = fmaf(v, w.z, acc[4 * j + 2]);
                acc[4 * j + 3] = fmaf(v, w.w, acc[4 * j + 3]);
              }
            }
          }
        }
      }
    }
  }

  const int y = tY + 2 * sy + py, x = tX + 2 * sx + px;
  float* dst = upT + (((size_t)b * HO + y) * HO + x) * CO + oh;
#pragma unroll
  for (int j = 0; j < 4; j++) {
    float4 o4;
    o4.x = acc[4 * j + 0] + bup[oh + 4 * j + 0];
    o4.y = acc[4 * j + 1] + bup[oh + 4 * j + 1];
    o4.z = acc[4 * j + 2] + bup[oh + 4 * j + 2];
    o4.w = acc[4 * j + 3] + bup[oh + 4 * j + 3];
    ((float4*)dst)[j] = o4;
  }
}

// ---------------- K2: 3x3 conv over concat(up NHWC, low NCHW) -> offsets+mask ----
// grid (8 xtiles, 8 ytiles, B*4 out-groups), block 256 = 16x16 pixels, 8 outs each
__global__ __launch_bounds__(256) void k_off(const float* __restrict__ low,
                                             const float* __restrict__ boff,
                                             float* __restrict__ ws) {
  __shared__ float lds[8][18][18];
  const float* upT = ws + UPT;
  const float* wt  = ws + WTOFF;
  float* fo = ws + FOO;

  const int t  = threadIdx.x;
  const int b  = blockIdx.z >> 2; const int g = blockIdx.z & 3;  // out group: oc = g*8+j
  const int tY = blockIdx.y * 16, tX = blockIdx.x * 16;
  const int sy = t >> 4, sx = t & 15;
  const int y = tY + sy, x = tX + sx;

  float acc[8];
#pragma unroll
  for (int j = 0; j < 8; j++) acc[j] = 0.f;

  for (int c0 = 0; c0 < CIN; c0 += 8) {
    __syncthreads();
    if (c0 < CO) {  // channels from up (NHWC): 8 contiguous floats per pixel
      for (int i = t; i < 324; i += 256) {
        int r = i / 18, cc = i - 18 * r;
        int gy = tY - 1 + r, gx = tX - 1 + cc;
        float4 a = {0, 0, 0, 0}, b4 = {0, 0, 0, 0};
        if (gy >= 0 && gy < HO && gx >= 0 && gx < HO) {
          const float4* ptr = (const float4*)(upT + (((size_t)b * HO + gy) * HO + gx) * CO + c0);
          a = ptr[0]; b4 = ptr[1];
        }
        lds[0][r][cc] = a.x;  lds[1][r][cc] = a.y;  lds[2][r][cc] = a.z;  lds[3][r][cc] = a.w;
        lds[4][r][cc] = b4.x; lds[5][r][cc] = b4.y; lds[6][r][cc] = b4.z; lds[7][r][cc] = b4.w;
      }
    } else {        // channels from low (NCHW planes)
      for (int i = t; i < 8 * 324; i += 256) {
        int cl = i / 324; int rem = i - 324 * cl; int r = rem / 18; int cc = rem - 18 * r;
        int gy = tY - 1 + r, gx = tX - 1 + cc;
        float v = 0.f;
        if (gy >= 0 && gy < HO && gx >= 0 && gx < HO)
          v = low[((size_t)(b * CO + (c0 - CO + cl)) * HO + gy) * HO + gx];
        lds[cl][r][cc] = v;
      }
    }
    __syncthreads();
#pragma unroll 2
    for (int cl = 0; cl < 8; cl++) {
      int c = c0 + cl;
#pragma unroll
      for (int ky = 0; ky < 3; ky++)
#pragma unroll
        for (int kx = 0; kx < 3; kx++) {
          float v = lds[cl][sy + ky][sx + kx];
          const float4* w4 = (const float4*)(wt + ((size_t)c * 9 + ky * 3 + kx) * 32 + g * 8);
          float4 w0 = w4[0], w1 = w4[1];
          acc[0] = fmaf(v, w0.x, acc[0]);
          acc[1] = fmaf(v, w0.y, acc[1]);
          acc[2] = fmaf(v, w0.z, acc[2]);
          acc[3] = fmaf(v, w0.w, acc[3]);
          acc[4] = fmaf(v, w1.x, acc[4]);
          acc[5] = fmaf(v, w1.y, acc[5]);
          acc[6] = fmaf(v, w1.z, acc[6]);
          acc[7] = fmaf(v, w1.w, acc[7]);
        }
    }
  }

#pragma unroll
  for (int j = 0; j < 8; j++) {
    int oc = g * 8 + j;
    if (oc < NOFF) {
      float v = acc[j] + boff[oc];
      if (oc >= 18) v = 2.f / (1.f + expf(-v));   // mask = 2*sigmoid
      fo[(((size_t)b * NOFF + oc) * HO + y) * HO + x] = v;
    }
  }
}

// ---------------- K3: modulated deformable conv + leaky relu ---------------------
// grid (8 xt, 16 yt, B), block 256 = 128 pixels (16x8) x 2 input-channel halves
__global__ __launch_bounds__(256) void k_dcn(const float* __restrict__ bal,
                                             float* __restrict__ out,
                                             const float* __restrict__ ws) {
  __shared__ float red[128 * 17];
  const float* upT = ws + UPT;
  const float* fo  = ws + FOO;
  const float* wt  = ws + WTAL;

  const int t   = threadIdx.x;
  const int h   = t >> 7;            // input-channel half: c in [h*32, h*32+32)
  const int tid = t & 127;
  const int b   = blockIdx.z;
  const int tY  = blockIdx.y * 8, tX = blockIdx.x * 16;
  const int sy  = tid >> 4, sx = tid & 15;
  const int y = tY + sy, x = tX + sx;
  const int c0 = h * 32;

  float acc[64];
#pragma unroll
  for (int j = 0; j < 64; j++) acc[j] = 0.f;

  const float* foB = fo + (size_t)b * NOFF * HW + y * HO + x;
  const float* upB = upT + (size_t)b * HW * CO + c0;

#pragma unroll 1
  for (int k = 0; k < 9; k++) {
    int ky = k / 3, kx = k % 3;
    float offy = foB[(size_t)(2 * k) * HW];
    float offx = foB[(size_t)(2 * k + 1) * HW];
    float m    = foB[(size_t)(18 + k) * HW];
    float pyf = offy + (float)(y - 1 + ky);
    float pxf = offx + (float)(x - 1 + kx);
    float y0f = floorf(pyf), x0f = floorf(pxf);
    float wy = pyf - y0f, wx = pxf - x0f;
    int y0 = (int)y0f, x0 = (int)x0f;
    int y1 = y0 + 1, x1 = x0 + 1;
    float vy0 = (y0 >= 0 && y0 < HO) ? 1.f : 0.f;
    float vy1 = (y1 >= 0 && y1 < HO) ? 1.f : 0.f;
    float vx0 = (x0 >= 0 && x0 < HO) ? 1.f : 0.f;
    float vx1 = (x1 >= 0 && x1 < HO) ? 1.f : 0.f;
    float w00 = (1.f - wy) * (1.f - wx) * vy0 * vx0 * m;
    float w01 = (1.f - wy) * wx         * vy0 * vx1 * m;
    float w10 = wy         * (1.f - wx) * vy1 * vx0 * m;
    float w11 = wy         * wx         * vy1 * vx1 * m;
    int cy0 = min(max(y0, 0), HO - 1), cy1 = min(max(y1, 0), HO - 1);
    int cx0 = min(max(x0, 0), HO - 1), cx1 = min(max(x1, 0), HO - 1);
    const float4* p00 = (const float4*)(upB + ((size_t)cy0 * HO + cx0) * CO);
    const float4* p01 = (const float4*)(upB + ((size_t)cy0 * HO + cx1) * CO);
    const float4* p10 = (const float4*)(upB + ((size_t)cy1 * HO + cx0) * CO);
    const float4* p11 = (const float4*)(upB + ((size_t)cy1 * HO + cx1) * CO);
    const float* wk = wt + (size_t)k * CO * CO + (size_t)c0 * CO;

#pragma unroll 2
    for (int c4 = 0; c4 < 8; c4++) {
      float4 a00 = p00[c4], a01 = p01[c4], a10 = p10[c4], a11 = p11[c4];
      float vv[4];
      vv[0] = fmaf(w00, a00.x, fmaf(w01, a01.x, fmaf(w10, a10.x, w11 * a11.x)));
      vv[1] = fmaf(w00, a00.y, fmaf(w01, a01.y, fmaf(w10, a10.y, w11 * a11.y)));
      vv[2] = fmaf(w00, a00.z, fmaf(w01, a01.z, fmaf(w10, a10.z, w11 * a11.z)));
      vv[3] = fmaf(w00, a00.w, fmaf(w01, a01.w, fmaf(w10, a10.w, w11 * a11.w)));
#pragma unroll
      for (int cc = 0; cc < 4; cc++) {
        float vc = vv[cc];
        const float4* w4 = (const float4*)(wk + (size_t)(c4 * 4 + cc) * CO);
#pragma unroll
        for (int j = 0; j < 16; j++) {
          float4 w = w4[j];
          acc[4 * j + 0] = fmaf(vc, w.x, acc[4 * j + 0]);
          acc[4 * j + 1] = fmaf(vc, w.y, acc[4 * j + 1]);
          acc[4 * j + 2] = fmaf(vc, w.z, acc[4 * j + 2]);
          acc[4 * j + 3] = fmaf(vc, w.w, acc[4 * j + 3]);
        }
      }
    }
  }

  // reduce the two channel-halves via LDS, 4 chunks of 16 outputs
#pragma unroll
  for (int chunk = 0; chunk < 4; chunk++) {
    if (h == 1) {
#pragma unroll
      for (int j = 0; j < 16; j++) red[tid * 17 + j] = acc[chunk * 16 + j];
    }
    __syncthreads();
    if (h == 0) {
#pragma unroll
      for (int j = 0; j < 16; j++) acc[chunk * 16 + j] += red[tid * 17 + j];
    }
    __syncthreads();
  }

  if (h == 0) {
    float* ob = out + (size_t)b * 2 * CO * HW + y * HO + x;
#pragma unroll
    for (int o = 0; o < 64; o++) {
      float v = acc[o] + bal[o];
      v = (v >= 0.f) ? v : 0.2f * v;          // leaky relu
      ob[(size_t)o * HW] = v;
    }
  }
}

// ---------------- K4: copy low_feature into out channels 64..127 -----------------
__global__ void k_copy(const float* __restrict__ low, float* __restrict__ out) {
  int i = blockIdx.x * 256 + threadIdx.x;       // over B*CO*HW/4 float4s
  int b = i >> 18;                              // 262144 float4 per batch
  float4 v = ((const float4*)low)[i];
  ((float4*)out)[i + (b + 1) * 262144] = v;
}

extern "C" void kernel_launch(void* const* d_in, const int* in_sizes, int n_in,
                              void* d_out, int out_size, void* d_ws, size_t ws_size,
                              hipStream_t stream) {
  const float* high = (const float*)d_in[0];
  const float* low  = (const float*)d_in[1];
  const float* wup  = (const float*)d_in[2];
  const float* bup  = (const float*)d_in[3];
  const float* woff = (const float*)d_in[4];
  const float* boff = (const float*)d_in[5];
  const float* wal  = (const float*)d_in[6];
  const float* bal  = (const float*)d_in[7];
  float* out = (float*)d_out;
  float* ws  = (float*)d_ws;

  k_repack<<<dim3(288), dim3(256), 0, stream>>>(wup, woff, wal, ws);
  k_up<<<dim3(16, 4, B * 4), dim3(256), 0, stream>>>(high, bup, ws);
  k_off<<<dim3(8, 8, B * 4), dim3(256), 0, stream>>>(low, boff, ws);
  k_dcn<<<dim3(8, 16, B), dim3(256), 0, stream>>>(bal, out, ws);
  k_copy<<<dim3(4096), dim3(256), 0, stream>>>(low, out);
}

// Round 3
// 596.326 us; speedup vs baseline: 1.1668x; 1.1668x over previous
//
#include <hip/hip_runtime.h>
#include <math.h>

namespace {
constexpr int B   = 4;
constexpr int CIN = 128;   // high channels
constexpr int CO  = 64;    // up / aligned channels
constexpr int HF  = 64;    // high H=W
constexpr int HO  = 128;   // up/out H=W
constexpr int HW  = HO * HO;   // 16384
constexpr int NOFF = 27;   // 18 offset + 9 mask channels

// workspace layout (float offsets)
constexpr size_t UPT   = 0;                          // [B][HO][HO][CO]  NHWC up
constexpr size_t FOO   = UPT  + (size_t)B * HW * CO; // [B][27][HO][HO]  offsets+mask
constexpr size_t WTUP  = FOO  + (size_t)B * NOFF * HW; // [3][3][CIN][CO]
constexpr size_t WTOFF = WTUP + (size_t)9 * CIN * CO;  // [CIN][9][32]
constexpr size_t WTAL  = WTOFF + (size_t)CIN * 9 * 32; // [9][CO][CO]
}

__device__ __forceinline__ unsigned short f2bf(float f) {
  unsigned u = __float_as_uint(f);
  u += 0x7fffu + ((u >> 16) & 1u);      // RNE
  return (unsigned short)(u >> 16);
}

// ---------------- weight repack: put output channel innermost (uniform s_load) ----
__global__ void k_repack(const float* __restrict__ wup, const float* __restrict__ woff,
                         const float* __restrict__ wal, float* __restrict__ ws) {
  int i = blockIdx.x * 256 + threadIdx.x;
  if (i < 9 * CIN * CO) {                 // src w_up[c][o][ry][rx] -> [ry][rx][c][o]
    int rx = i % 3; int t = i / 3; int ry = t % 3; t /= 3;
    int o = t % CO; int c = t / CO;
    ws[WTUP + ((size_t)(ry * 3 + rx) * CIN + c) * CO + o] = wup[i];
  }
  if (i < CIN * 9 * 32) {                 // dst [c][kt][32] from w_off[oc][c][ky][kx]
    int oc = i & 31; int t = i >> 5; int kt = t % 9; int c = t / 9;
    float v = 0.f;
    if (oc < NOFF) v = woff[((size_t)(oc * CIN + c) * 3 + kt / 3) * 3 + (kt % 3)];
    ws[WTOFF + i] = v;
  }
  if (i < 9 * CO * CO) {                  // dst [k][c][o] from w_align[o][c][k]
    int o = i & 63; int t = i >> 6; int c = t & 63; int k = t >> 6;
    ws[WTAL + i] = wal[((size_t)o * CO + c) * 9 + k];
  }
}

// ---------------- K1: transposed conv (parity-decomposed), NHWC output -----------
__global__ __launch_bounds__(256) void k_up(const float* __restrict__ high,
                                            const float* __restrict__ bup,
                                            float* __restrict__ ws) {
  __shared__ float lds[8][17][17];
  const float* wt = ws + WTUP;
  float* upT = ws + UPT;

  const int t  = threadIdx.x;
  const int p  = blockIdx.y; const int py = p >> 1, px = p & 1;
  const int b  = blockIdx.z >> 2; const int oh = (blockIdx.z & 3) * 16;
  const int tY = (blockIdx.x >> 2) * 32, tX = (blockIdx.x & 3) * 32;
  const int sy = t >> 4, sx = t & 15;
  const int iyB = tY >> 1, ixB = tX >> 1;

  float acc[16];
#pragma unroll
  for (int j = 0; j < 16; j++) acc[j] = 0.f;

  int relY[2], ryA[2], nty, relX[2], rxA[2], ntx;
  if (py == 0) { nty = 1; relY[0] = sy;     ryA[0] = 1; relY[1] = 0;      ryA[1] = 0; }
  else         { nty = 2; relY[0] = sy;     ryA[0] = 2; relY[1] = sy + 1; ryA[1] = 0; }
  if (px == 0) { ntx = 1; relX[0] = sx;     rxA[0] = 1; relX[1] = 0;      rxA[1] = 0; }
  else         { ntx = 2; relX[0] = sx;     rxA[0] = 2; relX[1] = sx + 1; rxA[1] = 0; }

  for (int c0 = 0; c0 < CIN; c0 += 8) {
    __syncthreads();
    for (int i = t; i < 8 * 289; i += 256) {
      int cl = i / 289; int rem = i - cl * 289; int r = rem / 17; int cc = rem - r * 17;
      int iy = iyB + r, ix = ixB + cc;
      float v = 0.f;
      if (iy < HF && ix < HF) v = high[((size_t)(b * CIN + c0 + cl) * HF + iy) * HF + ix];
      lds[cl][r][cc] = v;
    }
    __syncthreads();
#pragma unroll
    for (int cl = 0; cl < 8; cl++) {
      int c = c0 + cl;
#pragma unroll
      for (int ti = 0; ti < 2; ti++) {
        if (ti < nty) {
#pragma unroll
          for (int tj = 0; tj < 2; tj++) {
            if (tj < ntx) {
              float v = lds[cl][relY[ti]][relX[tj]];
              const float4* w4 =
                  (const float4*)(wt + ((size_t)(ryA[ti] * 3 + rxA[tj]) * CIN + c) * CO + oh);
#pragma unroll
              for (int j = 0; j < 4; j++) {
                float4 w = w4[j];
                acc[4 * j + 0] = fmaf(v, w.x, acc[4 * j + 0]);
                acc[4 * j + 1] = fmaf(v, w.y, acc[4 * j + 1]);
                acc[4 * j + 2] = fmaf(v, w.z, acc[4 * j + 2]);
                acc[4 * j + 3] = fmaf(v, w.w, acc[4 * j + 3]);
              }
            }
          }
        }
      }
    }
  }

  const int y = tY + 2 * sy + py, x = tX + 2 * sx + px;
  float* dst = upT + (((size_t)b * HO + y) * HO + x) * CO + oh;
#pragma unroll
  for (int j = 0; j < 4; j++) {
    float4 o4;
    o4.x = acc[4 * j + 0] + bup[oh + 4 * j + 0];
    o4.y = acc[4 * j + 1] + bup[oh + 4 * j + 1];
    o4.z = acc[4 * j + 2] + bup[oh + 4 * j + 2];
    o4.w = acc[4 * j + 3] + bup[oh + 4 * j + 3];
    ((float4*)dst)[j] = o4;
  }
}

// ---------------- K2: 3x3 conv over concat(up NHWC, low NCHW) -> offsets+mask ----
__global__ __launch_bounds__(256) void k_off(const float* __restrict__ low,
                                             const float* __restrict__ boff,
                                             float* __restrict__ ws) {
  __shared__ float lds[8][18][18];
  const float* upT = ws + UPT;
  const float* wt  = ws + WTOFF;
  float* fo = ws + FOO;

  const int t  = threadIdx.x;
  const int b  = blockIdx.z >> 2; const int g = blockIdx.z & 3;  // out group: oc = g*8+j
  const int tY = blockIdx.y * 16, tX = blockIdx.x * 16;
  const int sy = t >> 4, sx = t & 15;
  const int y = tY + sy, x = tX + sx;

  float acc[8];
#pragma unroll
  for (int j = 0; j < 8; j++) acc[j] = 0.f;

  for (int c0 = 0; c0 < CIN; c0 += 8) {
    __syncthreads();
    if (c0 < CO) {  // channels from up (NHWC): 8 contiguous floats per pixel
      for (int i = t; i < 324; i += 256) {
        int r = i / 18, cc = i - 18 * r;
        int gy = tY - 1 + r, gx = tX - 1 + cc;
        float4 a = {0, 0, 0, 0}, b4 = {0, 0, 0, 0};
        if (gy >= 0 && gy < HO && gx >= 0 && gx < HO) {
          const float4* ptr = (const float4*)(upT + (((size_t)b * HO + gy) * HO + gx) * CO + c0);
          a = ptr[0]; b4 = ptr[1];
        }
        lds[0][r][cc] = a.x;  lds[1][r][cc] = a.y;  lds[2][r][cc] = a.z;  lds[3][r][cc] = a.w;
        lds[4][r][cc] = b4.x; lds[5][r][cc] = b4.y; lds[6][r][cc] = b4.z; lds[7][r][cc] = b4.w;
      }
    } else {        // channels from low (NCHW planes)
      for (int i = t; i < 8 * 324; i += 256) {
        int cl = i / 324; int rem = i - 324 * cl; int r = rem / 18; int cc = rem - 18 * r;
        int gy = tY - 1 + r, gx = tX - 1 + cc;
        float v = 0.f;
        if (gy >= 0 && gy < HO && gx >= 0 && gx < HO)
          v = low[((size_t)(b * CO + (c0 - CO + cl)) * HO + gy) * HO + gx];
        lds[cl][r][cc] = v;
      }
    }
    __syncthreads();
#pragma unroll 2
    for (int cl = 0; cl < 8; cl++) {
      int c = c0 + cl;
#pragma unroll
      for (int ky = 0; ky < 3; ky++)
#pragma unroll
        for (int kx = 0; kx < 3; kx++) {
          float v = lds[cl][sy + ky][sx + kx];
          const float4* w4 = (const float4*)(wt + ((size_t)c * 9 + ky * 3 + kx) * 32 + g * 8);
          float4 w0 = w4[0], w1 = w4[1];
          acc[0] = fmaf(v, w0.x, acc[0]);
          acc[1] = fmaf(v, w0.y, acc[1]);
          acc[2] = fmaf(v, w0.z, acc[2]);
          acc[3] = fmaf(v, w0.w, acc[3]);
          acc[4] = fmaf(v, w1.x, acc[4]);
          acc[5] = fmaf(v, w1.y, acc[5]);
          acc[6] = fmaf(v, w1.z, acc[6]);
          acc[7] = fmaf(v, w1.w, acc[7]);
        }
    }
  }

#pragma unroll
  for (int j = 0; j < 8; j++) {
    int oc = g * 8 + j;
    if (oc < NOFF) {
      float v = acc[j] + boff[oc];
      if (oc >= 18) v = 2.f / (1.f + expf(-v));   // mask = 2*sigmoid
      fo[(((size_t)b * NOFF + oc) * HO + y) * HO + x] = v;
    }
  }
}

// ---------------- K3: modulated deformable conv + leaky relu ---------------------
// block 256 = 4 waves; tile = 64 px (16w x 4h); grid (8,32,B) = 1024 blocks.
// Phase A: coalesced channel-contiguous gathers -> bilinear -> bf16 V-tile in LDS.
// Phase B: per-pixel GEMM, wave-uniform weight addresses (s_load), acc[16]/thread.
__global__ __launch_bounds__(256) void k_dcn(const float* __restrict__ bal,
                                             float* __restrict__ out,
                                             const float* __restrict__ ws) {
  __shared__ float prm[9][64][5];                 // w00..w11 + packed corners
  __shared__ unsigned short Vt[2][8][64][8];      // [buf][ch-chunk][px][8ch] bf16

  const float* upT = ws + UPT;
  const float* fo  = ws + FOO;
  const float* wt  = ws + WTAL;

  const int t    = threadIdx.x;
  const int lane = t & 63;
  const int oq   = __builtin_amdgcn_readfirstlane(t >> 6);   // wave id 0..3
  const int b    = blockIdx.z;
  const int tY   = blockIdx.y * 4, tX = blockIdx.x * 16;
  const float* upB = upT + (size_t)b * HW * CO;

  // ---- params: per (tap, px): bilinear weights (mask+validity folded) + corners
  for (int i = t; i < 9 * 64; i += 256) {
    int k = i >> 6, px = i & 63;
    int y = tY + (px >> 4), x = tX + (px & 15);
    const float* foP = fo + (size_t)b * NOFF * HW + (size_t)y * HO + x;
    float offy = foP[(size_t)(2 * k) * HW];
    float offx = foP[(size_t)(2 * k + 1) * HW];
    float m    = foP[(size_t)(18 + k) * HW];
    float pyf = offy + (float)(y - 1 + k / 3);
    float pxf = offx + (float)(x - 1 + k % 3);
    float y0f = floorf(pyf), x0f = floorf(pxf);
    float wy = pyf - y0f, wx = pxf - x0f;
    int y0 = (int)y0f, x0 = (int)x0f;
    int y1 = y0 + 1, x1 = x0 + 1;
    float vy0 = (y0 >= 0 && y0 < HO) ? m : 0.f;    // fold mask into validity
    float vy1 = (y1 >= 0 && y1 < HO) ? m : 0.f;
    float vx0 = (x0 >= 0 && x0 < HO) ? 1.f : 0.f;
    float vx1 = (x1 >= 0 && x1 < HO) ? 1.f : 0.f;
    prm[k][px][0] = (1.f - wy) * (1.f - wx) * vy0 * vx0;
    prm[k][px][1] = (1.f - wy) * wx * vy0 * vx1;
    prm[k][px][2] = wy * (1.f - wx) * vy1 * vx0;
    prm[k][px][3] = wy * wx * vy1 * vx1;
    int cy0 = min(max(y0, 0), HO - 1), cy1 = min(max(y1, 0), HO - 1);
    int cx0 = min(max(x0, 0), HO - 1), cx1 = min(max(x1, 0), HO - 1);
    unsigned pc = (unsigned)cy0 | ((unsigned)cy1 << 8) |
                  ((unsigned)cx0 << 16) | ((unsigned)cx1 << 24);
    prm[k][px][4] = __uint_as_float(pc);
  }
  __syncthreads();

  float4 c00[4], c01[4], c10[4], c11[4];

  auto issue = [&](int k) {        // coalesced corner gathers: 16 lanes = 256B runs
#pragma unroll
    for (int it = 0; it < 4; ++it) {
      int j = it * 256 + t;
      int q = j & 15, px = j >> 4;
      unsigned pc = __float_as_uint(prm[k][px][4]);
      int cy0 = pc & 255, cy1 = (pc >> 8) & 255, cx0 = (pc >> 16) & 255, cx1 = pc >> 24;
      const float* base = upB + q * 4;
      c00[it] = *(const float4*)(base + (size_t)(cy0 * HO + cx0) * CO);
      c01[it] = *(const float4*)(base + (size_t)(cy0 * HO + cx1) * CO);
      c10[it] = *(const float4*)(base + (size_t)(cy1 * HO + cx0) * CO);
      c11[it] = *(const float4*)(base + (size_t)(cy1 * HO + cx1) * CO);
    }
  };

  auto combine = [&](int k, int buf) {
#pragma unroll
    for (int it = 0; it < 4; ++it) {
      int j = it * 256 + t;
      int q = j & 15, px = j >> 4;
      float w0 = prm[k][px][0], w1 = prm[k][px][1];
      float w2 = prm[k][px][2], w3 = prm[k][px][3];
      float vx = fmaf(w0, c00[it].x, fmaf(w1, c01[it].x, fmaf(w2, c10[it].x, w3 * c11[it].x)));
      float vy = fmaf(w0, c00[it].y, fmaf(w1, c01[it].y, fmaf(w2, c10[it].y, w3 * c11[it].y)));
      float vz = fmaf(w0, c00[it].z, fmaf(w1, c01[it].z, fmaf(w2, c10[it].z, w3 * c11[it].z)));
      float vw = fmaf(w0, c00[it].w, fmaf(w1, c01[it].w, fmaf(w2, c10[it].w, w3 * c11[it].w)));
      ushort4 st;
      st.x = f2bf(vx); st.y = f2bf(vy); st.z = f2bf(vz); st.w = f2bf(vw);
      *(ushort4*)&Vt[buf][q >> 1][px][(q & 1) * 4] = st;
    }
  };

  float acc[16];
#pragma unroll
  for (int j = 0; j < 16; j++) acc[j] = 0.f;

  issue(0);
  combine(0, 0);
  __syncthreads();

  int buf = 0;
#pragma unroll 1
  for (int k = 0; k < 9; ++k) {
    if (k < 8) issue(k + 1);                      // prefetch next tap's corners
    const float* wk = wt + (size_t)k * CO * CO + oq * 16;   // wave-uniform base
#pragma unroll
    for (int ch = 0; ch < 8; ++ch) {
      uint4 vv = *(const uint4*)&Vt[buf][ch][lane][0];
      unsigned uu[4] = {vv.x, vv.y, vv.z, vv.w};
#pragma unroll
      for (int p = 0; p < 4; ++p) {
        float lo = __uint_as_float(uu[p] << 16);
        float hi = __uint_as_float(uu[p] & 0xffff0000u);
        const float4* wlo = (const float4*)(wk + (size_t)(ch * 8 + 2 * p) * CO);
        const float4* whi = (const float4*)(wk + (size_t)(ch * 8 + 2 * p + 1) * CO);
#pragma unroll
        for (int jj = 0; jj < 4; ++jj) {
          float4 wa = wlo[jj], wb = whi[jj];
          acc[4 * jj + 0] = fmaf(lo, wa.x, acc[4 * jj + 0]);
          acc[4 * jj + 1] = fmaf(lo, wa.y, acc[4 * jj + 1]);
          acc[4 * jj + 2] = fmaf(lo, wa.z, acc[4 * jj + 2]);
          acc[4 * jj + 3] = fmaf(lo, wa.w, acc[4 * jj + 3]);
          acc[4 * jj + 0] = fmaf(hi, wb.x, acc[4 * jj + 0]);
          acc[4 * jj + 1] = fmaf(hi, wb.y, acc[4 * jj + 1]);
          acc[4 * jj + 2] = fmaf(hi, wb.z, acc[4 * jj + 2]);
          acc[4 * jj + 3] = fmaf(hi, wb.w, acc[4 * jj + 3]);
        }
      }
    }
    if (k < 8) combine(k + 1, buf ^ 1);
    __syncthreads();
    buf ^= 1;
  }

  const int y = tY + (lane >> 4), x = tX + (lane & 15);
  float* ob = out + (size_t)b * 2 * CO * HW + (size_t)y * HO + x;
#pragma unroll
  for (int j = 0; j < 16; ++j) {
    int o = oq * 16 + j;
    float v = acc[j] + bal[o];
    v = (v >= 0.f) ? v : 0.2f * v;                // leaky relu
    ob[(size_t)o * HW] = v;
  }
}

// ---------------- K4: copy low_feature into out channels 64..127 -----------------
__global__ void k_copy(const float* __restrict__ low, float* __restrict__ out) {
  int i = blockIdx.x * 256 + threadIdx.x;       // over B*CO*HW/4 float4s
  int b = i >> 18;                              // 262144 float4 per batch
  float4 v = ((const float4*)low)[i];
  ((float4*)out)[i + (b + 1) * 262144] = v;
}

extern "C" void kernel_launch(void* const* d_in, const int* in_sizes, int n_in,
                              void* d_out, int out_size, void* d_ws, size_t ws_size,
                              hipStream_t stream) {
  const float* high = (const float*)d_in[0];
  const float* low  = (const float*)d_in[1];
  const float* wup  = (const float*)d_in[2];
  const float* bup  = (const float*)d_in[3];
  const float* woff = (const float*)d_in[4];
  const float* boff = (const float*)d_in[5];
  const float* wal  = (const float*)d_in[6];
  const float* bal  = (const float*)d_in[7];
  float* out = (float*)d_out;
  float* ws  = (float*)d_ws;

  k_repack<<<dim3(288), dim3(256), 0, stream>>>(wup, woff, wal, ws);
  k_up<<<dim3(16, 4, B * 4), dim3(256), 0, stream>>>(high, bup, ws);
  k_off<<<dim3(8, 8, B * 4), dim3(256), 0, stream>>>(low, boff, ws);
  k_dcn<<<dim3(8, 32, B), dim3(256), 0, stream>>>(bal, out, ws);
  k_copy<<<dim3(4096), dim3(256), 0, stream>>>(low, out);
}

// Round 4
// 305.740 us; speedup vs baseline: 2.2757x; 1.9504x over previous
//
#include <hip/hip_runtime.h>
#include <math.h>

namespace {
constexpr int B   = 4;
constexpr int CIN = 128;   // high channels
constexpr int CO  = 64;    // up / aligned channels
constexpr int HF  = 64;    // high H=W
constexpr int HO  = 128;   // up/out H=W
constexpr int HW  = HO * HO;   // 16384
constexpr int NOFF = 27;   // 18 offset + 9 mask channels

// workspace layout (float offsets)
constexpr size_t UPT   = 0;                          // [B][HO][HO][CO]  NHWC up
constexpr size_t FOO   = UPT  + (size_t)B * HW * CO; // [B][27][HO][HO]  offsets+mask
constexpr size_t WTUP  = FOO  + (size_t)B * NOFF * HW; // [3][3][CIN][CO]
constexpr size_t WTOFF = WTUP + (size_t)9 * CIN * CO;  // [CIN][9][32]
constexpr size_t WTAL  = WTOFF + (size_t)CIN * 9 * 32; // [9][CO][CO]
constexpr size_t WFRG  = WTAL + (size_t)9 * CO * CO;   // bf16 B-frags [4][18][64][8]
}

using short8 = __attribute__((ext_vector_type(8))) short;
using f32x4  = __attribute__((ext_vector_type(4))) float;

__device__ __forceinline__ unsigned short f2bf(float f) {
  unsigned u = __float_as_uint(f);
  u += 0x7fffu + ((u >> 16) & 1u);      // RNE
  return (unsigned short)(u >> 16);
}

// ---------------- weight repack ---------------------------------------------------
__global__ void k_repack(const float* __restrict__ wup, const float* __restrict__ woff,
                         const float* __restrict__ wal, float* __restrict__ ws) {
  int i = blockIdx.x * 256 + threadIdx.x;
  if (i < 9 * CIN * CO) {                 // src w_up[c][o][ry][rx] -> [ry][rx][c][o]
    int rx = i % 3; int t = i / 3; int ry = t % 3; t /= 3;
    int o = t % CO; int c = t / CO;
    ws[WTUP + ((size_t)(ry * 3 + rx) * CIN + c) * CO + o] = wup[i];
  }
  if (i < CIN * 9 * 32) {                 // dst [c][kt][32] from w_off[oc][c][ky][kx]
    int oc = i & 31; int t = i >> 5; int kt = t % 9; int c = t / 9;
    float v = 0.f;
    if (oc < NOFF) v = woff[((size_t)(oc * CIN + c) * 3 + kt / 3) * 3 + (kt % 3)];
    ws[WTOFF + i] = v;
  }
  if (i < 9 * CO * CO) {                  // dst [k][c][o] from w_align[o][c][k]
    int o = i & 63; int t = i >> 6; int c = t & 63; int k = t >> 6;
    ws[WTAL + i] = wal[((size_t)o * CO + c) * 9 + k];
  }
  if (i < 4 * 18 * 64 * 8) {              // bf16 MFMA B-frags for k_dcn:
    int j = i & 7; int t2 = i >> 3;       // [w][kb][lane][j]; c = kb-chunk k-index
    int lane = t2 & 63; int t3 = t2 >> 6;
    int kb = t3 % 18; int w = t3 / 18;
    int tap = kb >> 1;
    int c = (kb & 1) * 32 + ((lane >> 4) << 3) + j;
    int o = (w << 4) + (lane & 15);
    unsigned short* wfrag = (unsigned short*)(ws + WFRG);
    wfrag[i] = f2bf(wal[((size_t)o * CO + c) * 9 + tap]);
  }
}

// ---------------- K1: transposed conv (parity-decomposed), NHWC output -----------
__global__ __launch_bounds__(256) void k_up(const float* __restrict__ high,
                                            const float* __restrict__ bup,
                                            float* __restrict__ ws) {
  __shared__ float lds[8][17][17];
  const float* wt = ws + WTUP;
  float* upT = ws + UPT;

  const int t  = threadIdx.x;
  const int p  = blockIdx.y; const int py = p >> 1, px = p & 1;
  const int b  = blockIdx.z >> 2; const int oh = (blockIdx.z & 3) * 16;
  const int tY = (blockIdx.x >> 2) * 32, tX = (blockIdx.x & 3) * 32;
  const int sy = t >> 4, sx = t & 15;
  const int iyB = tY >> 1, ixB = tX >> 1;

  float acc[16];
#pragma unroll
  for (int j = 0; j < 16; j++) acc[j] = 0.f;

  int relY[2], ryA[2], nty, relX[2], rxA[2], ntx;
  if (py == 0) { nty = 1; relY[0] = sy;     ryA[0] = 1; relY[1] = 0;      ryA[1] = 0; }
  else         { nty = 2; relY[0] = sy;     ryA[0] = 2; relY[1] = sy + 1; ryA[1] = 0; }
  if (px == 0) { ntx = 1; relX[0] = sx;     rxA[0] = 1; relX[1] = 0;      rxA[1] = 0; }
  else         { ntx = 2; relX[0] = sx;     rxA[0] = 2; relX[1] = sx + 1; rxA[1] = 0; }

  for (int c0 = 0; c0 < CIN; c0 += 8) {
    __syncthreads();
    for (int i = t; i < 8 * 289; i += 256) {
      int cl = i / 289; int rem = i - cl * 289; int r = rem / 17; int cc = rem - r * 17;
      int iy = iyB + r, ix = ixB + cc;
      float v = 0.f;
      if (iy < HF && ix < HF) v = high[((size_t)(b * CIN + c0 + cl) * HF + iy) * HF + ix];
      lds[cl][r][cc] = v;
    }
    __syncthreads();
#pragma unroll
    for (int cl = 0; cl < 8; cl++) {
      int c = c0 + cl;
#pragma unroll
      for (int ti = 0; ti < 2; ti++) {
        if (ti < nty) {
#pragma unroll
          for (int tj = 0; tj < 2; tj++) {
            if (tj < ntx) {
              float v = lds[cl][relY[ti]][relX[tj]];
              const float4* w4 =
                  (const float4*)(wt + ((size_t)(ryA[ti] * 3 + rxA[tj]) * CIN + c) * CO + oh);
#pragma unroll
              for (int j = 0; j < 4; j++) {
                float4 w = w4[j];
                acc[4 * j + 0] = fmaf(v, w.x, acc[4 * j + 0]);
                acc[4 * j + 1] = fmaf(v, w.y, acc[4 * j + 1]);
                acc[4 * j + 2] = fmaf(v, w.z, acc[4 * j + 2]);
                acc[4 * j + 3] = fmaf(v, w.w, acc[4 * j + 3]);
              }
            }
          }
        }
      }
    }
  }

  const int y = tY + 2 * sy + py, x = tX + 2 * sx + px;
  float* dst = upT + (((size_t)b * HO + y) * HO + x) * CO + oh;
#pragma unroll
  for (int j = 0; j < 4; j++) {
    float4 o4;
    o4.x = acc[4 * j + 0] + bup[oh + 4 * j + 0];
    o4.y = acc[4 * j + 1] + bup[oh + 4 * j + 1];
    o4.z = acc[4 * j + 2] + bup[oh + 4 * j + 2];
    o4.w = acc[4 * j + 3] + bup[oh + 4 * j + 3];
    ((float4*)dst)[j] = o4;
  }
}

// ---------------- K2: 3x3 conv over concat(up NHWC, low NCHW) -> offsets+mask ----
__global__ __launch_bounds__(256) void k_off(const float* __restrict__ low,
                                             const float* __restrict__ boff,
                                             float* __restrict__ ws) {
  __shared__ float lds[8][18][18];
  const float* upT = ws + UPT;
  const float* wt  = ws + WTOFF;
  float* fo = ws + FOO;

  const int t  = threadIdx.x;
  const int b  = blockIdx.z >> 2; const int g = blockIdx.z & 3;  // out group: oc = g*8+j
  const int tY = blockIdx.y * 16, tX = blockIdx.x * 16;
  const int sy = t >> 4, sx = t & 15;
  const int y = tY + sy, x = tX + sx;

  float acc[8];
#pragma unroll
  for (int j = 0; j < 8; j++) acc[j] = 0.f;

  for (int c0 = 0; c0 < CIN; c0 += 8) {
    __syncthreads();
    if (c0 < CO) {  // channels from up (NHWC): 8 contiguous floats per pixel
      for (int i = t; i < 324; i += 256) {
        int r = i / 18, cc = i - 18 * r;
        int gy = tY - 1 + r, gx = tX - 1 + cc;
        float4 a = {0, 0, 0, 0}, b4 = {0, 0, 0, 0};
        if (gy >= 0 && gy < HO && gx >= 0 && gx < HO) {
          const float4* ptr = (const float4*)(upT + (((size_t)b * HO + gy) * HO + gx) * CO + c0);
          a = ptr[0]; b4 = ptr[1];
        }
        lds[0][r][cc] = a.x;  lds[1][r][cc] = a.y;  lds[2][r][cc] = a.z;  lds[3][r][cc] = a.w;
        lds[4][r][cc] = b4.x; lds[5][r][cc] = b4.y; lds[6][r][cc] = b4.z; lds[7][r][cc] = b4.w;
      }
    } else {        // channels from low (NCHW planes)
      for (int i = t; i < 8 * 324; i += 256) {
        int cl = i / 324; int rem = i - 324 * cl; int r = rem / 18; int cc = rem - 18 * r;
        int gy = tY - 1 + r, gx = tX - 1 + cc;
        float v = 0.f;
        if (gy >= 0 && gy < HO && gx >= 0 && gx < HO)
          v = low[((size_t)(b * CO + (c0 - CO + cl)) * HO + gy) * HO + gx];
        lds[cl][r][cc] = v;
      }
    }
    __syncthreads();
#pragma unroll 2
    for (int cl = 0; cl < 8; cl++) {
      int c = c0 + cl;
#pragma unroll
      for (int ky = 0; ky < 3; ky++)
#pragma unroll
        for (int kx = 0; kx < 3; kx++) {
          float v = lds[cl][sy + ky][sx + kx];
          const float4* w4 = (const float4*)(wt + ((size_t)c * 9 + ky * 3 + kx) * 32 + g * 8);
          float4 w0 = w4[0], w1 = w4[1];
          acc[0] = fmaf(v, w0.x, acc[0]);
          acc[1] = fmaf(v, w0.y, acc[1]);
          acc[2] = fmaf(v, w0.z, acc[2]);
          acc[3] = fmaf(v, w0.w, acc[3]);
          acc[4] = fmaf(v, w1.x, acc[4]);
          acc[5] = fmaf(v, w1.y, acc[5]);
          acc[6] = fmaf(v, w1.z, acc[6]);
          acc[7] = fmaf(v, w1.w, acc[7]);
        }
    }
  }

#pragma unroll
  for (int j = 0; j < 8; j++) {
    int oc = g * 8 + j;
    if (oc < NOFF) {
      float v = acc[j] + boff[oc];
      if (oc >= 18) v = 2.f / (1.f + expf(-v));   // mask = 2*sigmoid
      fo[(((size_t)b * NOFF + oc) * HO + y) * HO + x] = v;
    }
  }
}

// ---------------- K3: modulated deformable conv (MFMA GEMM) + leaky relu ---------
// block 256 = 4 waves; tile 64 px (16x4); wave w owns out cols [16w,16w+16).
// Phase A: coalesced gathers -> bilinear -> bf16 V-tile (MFMA A-frag layout) in LDS.
// Phase B: mfma_f32_16x16x32_bf16, B-frags preloaded from repacked weights.
union SmemU {
  struct {
    float prm[9][64][5];                  // bilinear weights + packed corners
    unsigned short Vt[2][8][64][8];       // [buf][kchunk][px][8ch] bf16
  } s;
  float accs[4][16][65];                  // epilogue transpose (pad 65: conflict-free)
};

__global__ __launch_bounds__(256) void k_dcn(const float* __restrict__ bal,
                                             float* __restrict__ out,
                                             const float* __restrict__ ws) {
  __shared__ SmemU sm;
  const float* upT = ws + UPT;
  const float* fo  = ws + FOO;
  const uint4* wf  = (const uint4*)(ws + WFRG);   // [w][18][64] uint4 (bf16x8)

  const int t    = threadIdx.x;
  const int lane = t & 63;
  const int oq   = __builtin_amdgcn_readfirstlane(t >> 6);   // wave id 0..3
  const int b    = blockIdx.z;
  const int tY   = blockIdx.y * 4, tX = blockIdx.x * 16;
  const float* upB = upT + (size_t)b * HW * CO;

  // ---- params: per (tap, px): bilinear weights (mask+validity folded) + corners
  for (int i = t; i < 9 * 64; i += 256) {
    int k = i >> 6, px = i & 63;
    int y = tY + (px >> 4), x = tX + (px & 15);
    const float* foP = fo + (size_t)b * NOFF * HW + (size_t)y * HO + x;
    float offy = foP[(size_t)(2 * k) * HW];
    float offx = foP[(size_t)(2 * k + 1) * HW];
    float m    = foP[(size_t)(18 + k) * HW];
    float pyf = offy + (float)(y - 1 + k / 3);
    float pxf = offx + (float)(x - 1 + k % 3);
    float y0f = floorf(pyf), x0f = floorf(pxf);
    float wy = pyf - y0f, wx = pxf - x0f;
    int y0 = (int)y0f, x0 = (int)x0f;
    int y1 = y0 + 1, x1 = x0 + 1;
    float vy0 = (y0 >= 0 && y0 < HO) ? m : 0.f;    // fold mask into validity
    float vy1 = (y1 >= 0 && y1 < HO) ? m : 0.f;
    float vx0 = (x0 >= 0 && x0 < HO) ? 1.f : 0.f;
    float vx1 = (x1 >= 0 && x1 < HO) ? 1.f : 0.f;
    sm.s.prm[k][px][0] = (1.f - wy) * (1.f - wx) * vy0 * vx0;
    sm.s.prm[k][px][1] = (1.f - wy) * wx * vy0 * vx1;
    sm.s.prm[k][px][2] = wy * (1.f - wx) * vy1 * vx0;
    sm.s.prm[k][px][3] = wy * wx * vy1 * vx1;
    int cy0 = min(max(y0, 0), HO - 1), cy1 = min(max(y1, 0), HO - 1);
    int cx0 = min(max(x0, 0), HO - 1), cx1 = min(max(x1, 0), HO - 1);
    unsigned pc = (unsigned)cy0 | ((unsigned)cy1 << 8) |
                  ((unsigned)cx0 << 16) | ((unsigned)cx1 << 24);
    sm.s.prm[k][px][4] = __uint_as_float(pc);
  }
  __syncthreads();

  float4 c00[4], c01[4], c10[4], c11[4];

  auto issue = [&](int k) {        // coalesced corner gathers: 16 lanes = 256B runs
#pragma unroll
    for (int it = 0; it < 4; ++it) {
      int j = it * 256 + t;
      int q = j & 15, px = j >> 4;
      unsigned pc = __float_as_uint(sm.s.prm[k][px][4]);
      int cy0 = pc & 255, cy1 = (pc >> 8) & 255, cx0 = (pc >> 16) & 255, cx1 = pc >> 24;
      const float* base = upB + q * 4;
      c00[it] = *(const float4*)(base + (size_t)(cy0 * HO + cx0) * CO);
      c01[it] = *(const float4*)(base + (size_t)(cy0 * HO + cx1) * CO);
      c10[it] = *(const float4*)(base + (size_t)(cy1 * HO + cx0) * CO);
      c11[it] = *(const float4*)(base + (size_t)(cy1 * HO + cx1) * CO);
    }
  };

  auto combine = [&](int k, int buf) {
#pragma unroll
    for (int it = 0; it < 4; ++it) {
      int j = it * 256 + t;
      int q = j & 15, px = j >> 4;
      float w0 = sm.s.prm[k][px][0], w1 = sm.s.prm[k][px][1];
      float w2 = sm.s.prm[k][px][2], w3 = sm.s.prm[k][px][3];
      float vx = fmaf(w0, c00[it].x, fmaf(w1, c01[it].x, fmaf(w2, c10[it].x, w3 * c11[it].x)));
      float vy = fmaf(w0, c00[it].y, fmaf(w1, c01[it].y, fmaf(w2, c10[it].y, w3 * c11[it].y)));
      float vz = fmaf(w0, c00[it].z, fmaf(w1, c01[it].z, fmaf(w2, c10[it].z, w3 * c11[it].z)));
      float vw = fmaf(w0, c00[it].w, fmaf(w1, c01[it].w, fmaf(w2, c10[it].w, w3 * c11[it].w)));
      ushort4 st;
      st.x = f2bf(vx); st.y = f2bf(vy); st.z = f2bf(vz); st.w = f2bf(vw);
      *(ushort4*)&sm.s.Vt[buf][q >> 1][px][(q & 1) * 4] = st;
    }
  };

  f32x4 acc[4];
#pragma unroll
  for (int mt = 0; mt < 4; ++mt) acc[mt] = {0.f, 0.f, 0.f, 0.f};

  // preload first tap's B-frags (coalesced, L2-resident)
  uint4 bw0 = wf[(oq * 18 + 0) * 64 + lane];
  uint4 bw1 = wf[(oq * 18 + 1) * 64 + lane];
  uint4 bn0, bn1;

  issue(0);
  combine(0, 0);
  __syncthreads();

  union Cvt { uint4 u; short8 s; };
  int buf = 0;
#pragma unroll 1
  for (int k = 0; k < 9; ++k) {
    if (k < 8) {
      issue(k + 1);
      bn0 = wf[(oq * 18 + 2 * k + 2) * 64 + lane];
      bn1 = wf[(oq * 18 + 2 * k + 3) * 64 + lane];
    }
    // MFMA phase: 2 k-chunks x 4 M-tiles
#pragma unroll
    for (int kb2 = 0; kb2 < 2; ++kb2) {
      Cvt bfr; bfr.u = kb2 ? bw1 : bw0;
#pragma unroll
      for (int mt = 0; mt < 4; ++mt) {
        Cvt av;
        av.u = *(const uint4*)&sm.s.Vt[buf][kb2 * 4 + (lane >> 4)][mt * 16 + (lane & 15)][0];
        acc[mt] = __builtin_amdgcn_mfma_f32_16x16x32_bf16(av.s, bfr.s, acc[mt], 0, 0, 0);
      }
    }
    if (k < 8) combine(k + 1, buf ^ 1);
    __syncthreads();
    bw0 = bn0; bw1 = bn1;
    buf ^= 1;
  }

  // epilogue: transpose acc via padded LDS, coalesced store + bias + leaky relu
#pragma unroll
  for (int mt = 0; mt < 4; ++mt)
#pragma unroll
    for (int r = 0; r < 4; ++r)
      sm.accs[oq][lane & 15][mt * 16 + (lane >> 4) * 4 + r] = acc[mt][r];
  __syncthreads();

  const int y = tY + (lane >> 4), x = tX + (lane & 15);
  float* ob = out + (size_t)b * 2 * CO * HW + (size_t)y * HO + x;
#pragma unroll
  for (int ol = 0; ol < 16; ++ol) {
    int o = oq * 16 + ol;
    float v = sm.accs[oq][ol][lane] + bal[o];
    v = (v >= 0.f) ? v : 0.2f * v;                // leaky relu
    ob[(size_t)o * HW] = v;
  }
}

// ---------------- K4: copy low_feature into out channels 64..127 -----------------
__global__ void k_copy(const float* __restrict__ low, float* __restrict__ out) {
  int i = blockIdx.x * 256 + threadIdx.x;       // over B*CO*HW/4 float4s
  int b = i >> 18;                              // 262144 float4 per batch
  float4 v = ((const float4*)low)[i];
  ((float4*)out)[i + (b + 1) * 262144] = v;
}

extern "C" void kernel_launch(void* const* d_in, const int* in_sizes, int n_in,
                              void* d_out, int out_size, void* d_ws, size_t ws_size,
                              hipStream_t stream) {
  const float* high = (const float*)d_in[0];
  const float* low  = (const float*)d_in[1];
  const float* wup  = (const float*)d_in[2];
  const float* bup  = (const float*)d_in[3];
  const float* woff = (const float*)d_in[4];
  const float* boff = (const float*)d_in[5];
  const float* wal  = (const float*)d_in[6];
  const float* bal  = (const float*)d_in[7];
  float* out = (float*)d_out;
  float* ws  = (float*)d_ws;

  k_repack<<<dim3(288), dim3(256), 0, stream>>>(wup, woff, wal, ws);
  k_up<<<dim3(16, 4, B * 4), dim3(256), 0, stream>>>(high, bup, ws);
  k_off<<<dim3(8, 8, B * 4), dim3(256), 0, stream>>>(low, boff, ws);
  k_dcn<<<dim3(8, 32, B), dim3(256), 0, stream>>>(bal, out, ws);
  k_copy<<<dim3(4096), dim3(256), 0, stream>>>(low, out);
}

// Round 5
// 173.362 us; speedup vs baseline: 4.0135x; 1.7636x over previous
//
#include <hip/hip_runtime.h>
#include <math.h>

namespace {
constexpr int B   = 4;
constexpr int CIN = 128;   // high channels
constexpr int CO  = 64;    // up / aligned channels
constexpr int HF  = 64;    // high H=W
constexpr int HO  = 128;   // up/out H=W
constexpr int HW  = HO * HO;   // 16384
constexpr int NOFF = 27;   // 18 offset + 9 mask channels

// workspace layout (float offsets)
constexpr size_t UPT   = 0;                          // [B][HO][HO][CO]  NHWC up
constexpr size_t FOO   = UPT  + (size_t)B * HW * CO; // [B][27][HO][HO]  offsets+mask
                                                     // (k_cvt's bf16 NHWC high overlays
                                                     //  this region until k_off rewrites it)
constexpr size_t WTUP  = FOO  + (size_t)B * NOFF * HW; // [3][3][CIN][CO]
constexpr size_t WTOFF = WTUP + (size_t)9 * CIN * CO;  // [CIN][9][32]
constexpr size_t WTAL  = WTOFF + (size_t)CIN * 9 * 32; // [9][CO][CO]
constexpr size_t WFRG  = WTAL + (size_t)9 * CO * CO;   // k_dcn bf16 B-frags [4][18][64][8]
constexpr size_t WFUP  = WFRG + (size_t)(4 * 18 * 64 * 8) / 2; // k_up bf16 B-frags [9][4][4][64][8]
}

using short8 = __attribute__((ext_vector_type(8))) short;
using f32x4  = __attribute__((ext_vector_type(4))) float;

__device__ __forceinline__ unsigned short f2bf(float f) {
  unsigned u = __float_as_uint(f);
  u += 0x7fffu + ((u >> 16) & 1u);      // RNE
  return (unsigned short)(u >> 16);
}

// ---------------- weight repack ---------------------------------------------------
__global__ void k_repack(const float* __restrict__ wup, const float* __restrict__ woff,
                         const float* __restrict__ wal, float* __restrict__ ws) {
  int i = blockIdx.x * 256 + threadIdx.x;
  if (i < CIN * 9 * 32) {                 // dst [c][kt][32] from w_off[oc][c][ky][kx]
    int oc = i & 31; int t = i >> 5; int kt = t % 9; int c = t / 9;
    float v = 0.f;
    if (oc < NOFF) v = woff[((size_t)(oc * CIN + c) * 3 + kt / 3) * 3 + (kt % 3)];
    ws[WTOFF + i] = v;
  }
  if (i < 4 * 18 * 64 * 8) {              // bf16 MFMA B-frags for k_dcn:
    int j = i & 7; int t2 = i >> 3;       // [w][kb][lane][j]; c = kb-chunk k-index
    int lane = t2 & 63; int t3 = t2 >> 6;
    int kb = t3 % 18; int w = t3 / 18;
    int tap = kb >> 1;
    int c = (kb & 1) * 32 + ((lane >> 4) << 3) + j;
    int o = (w << 4) + (lane & 15);
    unsigned short* wfrag = (unsigned short*)(ws + WFRG);
    wfrag[i] = f2bf(wal[((size_t)o * CO + c) * 9 + tap]);
  }
  if (i < 9 * 4 * 4 * 64 * 8) {           // bf16 MFMA B-frags for k_up: [rr][ch][w][lane][j]
    int j = i & 7; int lane = (i >> 3) & 63; int w = (i >> 9) & 3;
    int ch = (i >> 11) & 3; int rr = i >> 13;
    int c = ch * 32 + ((lane >> 4) << 3) + j;
    int o = w * 16 + (lane & 15);
    unsigned short* wfup = (unsigned short*)(ws + WFUP);
    wfup[i] = f2bf(wup[((size_t)c * CO + o) * 9 + rr]);
  }
}

// ---------------- K0: convert high fp32 NCHW -> bf16 NHWC (into FOO region) -------
__global__ __launch_bounds__(256) void k_cvt(const float* __restrict__ high,
                                             float* __restrict__ ws) {
  __shared__ unsigned short tl[32][66];
  unsigned short* hbf = (unsigned short*)(ws + FOO);
  const int t = threadIdx.x;
  const int y = blockIdx.x, b = blockIdx.y;
  const int x = t & 63, clb = t >> 6;

  for (int c0 = 0; c0 < CIN; c0 += 32) {
    __syncthreads();
#pragma unroll
    for (int k = 0; k < 8; ++k) {
      int cl = clb * 8 + k;
      float v = high[(((size_t)b * CIN + c0 + cl) * HF + y) * HF + x];
      tl[cl][x] = f2bf(v);
    }
    __syncthreads();
    int px = t >> 2, cg = t & 3;
    ushort4 a, bb;
    a.x = tl[cg * 8 + 0][px]; a.y = tl[cg * 8 + 1][px];
    a.z = tl[cg * 8 + 2][px]; a.w = tl[cg * 8 + 3][px];
    bb.x = tl[cg * 8 + 4][px]; bb.y = tl[cg * 8 + 5][px];
    bb.z = tl[cg * 8 + 6][px]; bb.w = tl[cg * 8 + 7][px];
    unsigned short* dst = hbf + (((size_t)b * HF + y) * HF + px) * CIN + c0 + cg * 8;
    *(ushort4*)(dst) = a;
    *(ushort4*)(dst + 4) = bb;
  }
}

// ---------------- K1: transposed conv as per-parity MFMA GEMM, NHWC fp32 out -----
// grid (4 xt, 16 yt, B*4 parity); block 256 = 4 waves; wave w owns o in [16w,16w+16).
// Tile: 64 parity-px (16 x-wide, 4 y-tall); K = CIN per tap, ntaps = (py+1)(px+1).
union SmemUp {
  unsigned short At[2][4][85][8];       // [buf][cg][5*17 px][8ch] bf16
  float accs[4][16][65];                // epilogue transpose (pad 65)
};

__global__ __launch_bounds__(256) void k_up(const float* __restrict__ bup,
                                            float* __restrict__ ws) {
  __shared__ SmemUp sm;
  const unsigned short* hbf = (const unsigned short*)(ws + FOO);
  const uint4* wfu = (const uint4*)(ws + WFUP);
  float* upT = ws + UPT;

  const int t    = threadIdx.x;
  const int lane = t & 63;
  const int oq   = __builtin_amdgcn_readfirstlane(t >> 6);
  const int z    = blockIdx.z;
  const int b    = z >> 2;
  const int pyv  = (z >> 1) & 1, pxv = z & 1;
  const int ty   = blockIdx.y * 4;      // parity-space row base (input rows ty..ty+4)
  const int tx   = blockIdx.x * 16;     // parity-space col base (input cols tx..tx+16)
  const int nty  = pyv + 1, ntx = pxv + 1;

  // staging: 85 px x 4 cgroups = 340 uint4 items; thread handles t and t+256
  uint4 s0, s1;
  const int pxA = t >> 2, cgA = t & 3;
  const int i2 = t + 256, pxB = i2 >> 2, cgB = i2 & 3;

  auto load_chunk = [&](int c0) {
    {
      int gy = ty + pxA / 17, gx = tx + pxA % 17;
      s0 = make_uint4(0, 0, 0, 0);
      if (gy < HF && gx < HF)
        s0 = *(const uint4*)(hbf + (((size_t)b * HF + gy) * HF + gx) * CIN + c0 + cgA * 8);
    }
    s1 = make_uint4(0, 0, 0, 0);
    if (pxB < 85) {
      int gy = ty + pxB / 17, gx = tx + pxB % 17;
      if (gy < HF && gx < HF)
        s1 = *(const uint4*)(hbf + (((size_t)b * HF + gy) * HF + gx) * CIN + c0 + cgB * 8);
    }
  };
  auto write_chunk = [&](int buf) {
    *(uint4*)&sm.At[buf][cgA][pxA][0] = s0;
    if (pxB < 85) *(uint4*)&sm.At[buf][cgB][pxB][0] = s1;
  };

  f32x4 acc[4];
#pragma unroll
  for (int mt = 0; mt < 4; ++mt) acc[mt] = {0.f, 0.f, 0.f, 0.f};

  load_chunk(0);
  write_chunk(0);
  __syncthreads();

  union Cvt { uint4 u; short8 s; };
  int buf = 0;
#pragma unroll 1
  for (int ch = 0; ch < 4; ++ch) {
    if (ch < 3) load_chunk((ch + 1) * 32);
#pragma unroll
    for (int ti = 0; ti < 2; ++ti) {
      if (ti < nty) {
#pragma unroll
        for (int tj = 0; tj < 2; ++tj) {
          if (tj < ntx) {
            int ryA = pyv ? 2 - 2 * ti : 1;
            int rxA = pxv ? 2 - 2 * tj : 1;
            int rr = ryA * 3 + rxA;
            Cvt bw; bw.u = wfu[(((size_t)rr * 4 + ch) * 4 + oq) * 64 + lane];
#pragma unroll
            for (int mt = 0; mt < 4; ++mt) {
              Cvt av;
              av.u = *(const uint4*)&sm.At[buf][lane >> 4][(mt + ti) * 17 + (lane & 15) + tj][0];
              acc[mt] = __builtin_amdgcn_mfma_f32_16x16x32_bf16(av.s, bw.s, acc[mt], 0, 0, 0);
            }
          }
        }
      }
    }
    if (ch < 3) write_chunk(buf ^ 1);
    __syncthreads();
    buf ^= 1;
  }

  // epilogue: transpose via padded LDS, coalesced NHWC stores + bias
#pragma unroll
  for (int mt = 0; mt < 4; ++mt)
#pragma unroll
    for (int r = 0; r < 4; ++r)
      sm.accs[oq][lane & 15][mt * 16 + (lane >> 4) * 4 + r] = acc[mt][r];
  __syncthreads();

  const int yo = 2 * (ty + (lane >> 4)) + pyv;
  const int xo = 2 * (tx + (lane & 15)) + pxv;
  float* dst = upT + (((size_t)b * HO + yo) * HO + xo) * CO + oq * 16;
#pragma unroll
  for (int j4 = 0; j4 < 4; ++j4) {
    float4 o4;
    o4.x = sm.accs[oq][j4 * 4 + 0][lane] + bup[oq * 16 + j4 * 4 + 0];
    o4.y = sm.accs[oq][j4 * 4 + 1][lane] + bup[oq * 16 + j4 * 4 + 1];
    o4.z = sm.accs[oq][j4 * 4 + 2][lane] + bup[oq * 16 + j4 * 4 + 2];
    o4.w = sm.accs[oq][j4 * 4 + 3][lane] + bup[oq * 16 + j4 * 4 + 3];
    ((float4*)dst)[j4] = o4;
  }
}

// ---------------- K2: 3x3 conv over concat(up NHWC, low NCHW) -> offsets+mask ----
__global__ __launch_bounds__(256) void k_off(const float* __restrict__ low,
                                             const float* __restrict__ boff,
                                             float* __restrict__ ws) {
  __shared__ float lds[8][18][18];
  const float* upT = ws + UPT;
  const float* wt  = ws + WTOFF;
  float* fo = ws + FOO;

  const int t  = threadIdx.x;
  const int b  = blockIdx.z >> 2; const int g = blockIdx.z & 3;  // out group: oc = g*8+j
  const int tY = blockIdx.y * 16, tX = blockIdx.x * 16;
  const int sy = t >> 4, sx = t & 15;
  const int y = tY + sy, x = tX + sx;

  float acc[8];
#pragma unroll
  for (int j = 0; j < 8; j++) acc[j] = 0.f;

  for (int c0 = 0; c0 < CIN; c0 += 8) {
    __syncthreads();
    if (c0 < CO) {  // channels from up (NHWC): 8 contiguous floats per pixel
      for (int i = t; i < 324; i += 256) {
        int r = i / 18, cc = i - 18 * r;
        int gy = tY - 1 + r, gx = tX - 1 + cc;
        float4 a = {0, 0, 0, 0}, b4 = {0, 0, 0, 0};
        if (gy >= 0 && gy < HO && gx >= 0 && gx < HO) {
          const float4* ptr = (const float4*)(upT + (((size_t)b * HO + gy) * HO + gx) * CO + c0);
          a = ptr[0]; b4 = ptr[1];
        }
        lds[0][r][cc] = a.x;  lds[1][r][cc] = a.y;  lds[2][r][cc] = a.z;  lds[3][r][cc] = a.w;
        lds[4][r][cc] = b4.x; lds[5][r][cc] = b4.y; lds[6][r][cc] = b4.z; lds[7][r][cc] = b4.w;
      }
    } else {        // channels from low (NCHW planes)
      for (int i = t; i < 8 * 324; i += 256) {
        int cl = i / 324; int rem = i - 324 * cl; int r = rem / 18; int cc = rem - 18 * r;
        int gy = tY - 1 + r, gx = tX - 1 + cc;
        float v = 0.f;
        if (gy >= 0 && gy < HO && gx >= 0 && gx < HO)
          v = low[((size_t)(b * CO + (c0 - CO + cl)) * HO + gy) * HO + gx];
        lds[cl][r][cc] = v;
      }
    }
    __syncthreads();
#pragma unroll 2
    for (int cl = 0; cl < 8; cl++) {
      int c = c0 + cl;
#pragma unroll
      for (int ky = 0; ky < 3; ky++)
#pragma unroll
        for (int kx = 0; kx < 3; kx++) {
          float v = lds[cl][sy + ky][sx + kx];
          const float4* w4 = (const float4*)(wt + ((size_t)c * 9 + ky * 3 + kx) * 32 + g * 8);
          float4 w0 = w4[0], w1 = w4[1];
          acc[0] = fmaf(v, w0.x, acc[0]);
          acc[1] = fmaf(v, w0.y, acc[1]);
          acc[2] = fmaf(v, w0.z, acc[2]);
          acc[3] = fmaf(v, w0.w, acc[3]);
          acc[4] = fmaf(v, w1.x, acc[4]);
          acc[5] = fmaf(v, w1.y, acc[5]);
          acc[6] = fmaf(v, w1.z, acc[6]);
          acc[7] = fmaf(v, w1.w, acc[7]);
        }
    }
  }

#pragma unroll
  for (int j = 0; j < 8; j++) {
    int oc = g * 8 + j;
    if (oc < NOFF) {
      float v = acc[j] + boff[oc];
      if (oc >= 18) v = 2.f / (1.f + expf(-v));   // mask = 2*sigmoid
      fo[(((size_t)b * NOFF + oc) * HO + y) * HO + x] = v;
    }
  }
}

// ---------------- K3: modulated deformable conv (MFMA GEMM) + leaky relu ---------
union SmemU {
  struct {
    float prm[9][64][5];                  // bilinear weights + packed corners
    unsigned short Vt[2][8][64][8];       // [buf][kchunk][px][8ch] bf16
  } s;
  float accs[4][16][65];                  // epilogue transpose (pad 65: conflict-free)
};

__global__ __launch_bounds__(256) void k_dcn(const float* __restrict__ bal,
                                             float* __restrict__ out,
                                             const float* __restrict__ ws) {
  __shared__ SmemU sm;
  const float* upT = ws + UPT;
  const float* fo  = ws + FOO;
  const uint4* wf  = (const uint4*)(ws + WFRG);   // [w][18][64] uint4 (bf16x8)

  const int t    = threadIdx.x;
  const int lane = t & 63;
  const int oq   = __builtin_amdgcn_readfirstlane(t >> 6);   // wave id 0..3
  const int b    = blockIdx.z;
  const int tY   = blockIdx.y * 4, tX = blockIdx.x * 16;
  const float* upB = upT + (size_t)b * HW * CO;

  // ---- params: per (tap, px): bilinear weights (mask+validity folded) + corners
  for (int i = t; i < 9 * 64; i += 256) {
    int k = i >> 6, px = i & 63;
    int y = tY + (px >> 4), x = tX + (px & 15);
    const float* foP = fo + (size_t)b * NOFF * HW + (size_t)y * HO + x;
    float offy = foP[(size_t)(2 * k) * HW];
    float offx = foP[(size_t)(2 * k + 1) * HW];
    float m    = foP[(size_t)(18 + k) * HW];
    float pyf = offy + (float)(y - 1 + k / 3);
    float pxf = offx + (float)(x - 1 + k % 3);
    float y0f = floorf(pyf), x0f = floorf(pxf);
    float wy = pyf - y0f, wx = pxf - x0f;
    int y0 = (int)y0f, x0 = (int)x0f;
    int y1 = y0 + 1, x1 = x0 + 1;
    float vy0 = (y0 >= 0 && y0 < HO) ? m : 0.f;    // fold mask into validity
    float vy1 = (y1 >= 0 && y1 < HO) ? m : 0.f;
    float vx0 = (x0 >= 0 && x0 < HO) ? 1.f : 0.f;
    float vx1 = (x1 >= 0 && x1 < HO) ? 1.f : 0.f;
    sm.s.prm[k][px][0] = (1.f - wy) * (1.f - wx) * vy0 * vx0;
    sm.s.prm[k][px][1] = (1.f - wy) * wx * vy0 * vx1;
    sm.s.prm[k][px][2] = wy * (1.f - wx) * vy1 * vx0;
    sm.s.prm[k][px][3] = wy * wx * vy1 * vx1;
    int cy0 = min(max(y0, 0), HO - 1), cy1 = min(max(y1, 0), HO - 1);
    int cx0 = min(max(x0, 0), HO - 1), cx1 = min(max(x1, 0), HO - 1);
    unsigned pc = (unsigned)cy0 | ((unsigned)cy1 << 8) |
                  ((unsigned)cx0 << 16) | ((unsigned)cx1 << 24);
    sm.s.prm[k][px][4] = __uint_as_float(pc);
  }
  __syncthreads();

  float4 c00[4], c01[4], c10[4], c11[4];

  auto issue = [&](int k) {        // coalesced corner gathers: 16 lanes = 256B runs
#pragma unroll
    for (int it = 0; it < 4; ++it) {
      int j = it * 256 + t;
      int q = j & 15, px = j >> 4;
      unsigned pc = __float_as_uint(sm.s.prm[k][px][4]);
      int cy0 = pc & 255, cy1 = (pc >> 8) & 255, cx0 = (pc >> 16) & 255, cx1 = pc >> 24;
      const float* base = upB + q * 4;
      c00[it] = *(const float4*)(base + (size_t)(cy0 * HO + cx0) * CO);
      c01[it] = *(const float4*)(base + (size_t)(cy0 * HO + cx1) * CO);
      c10[it] = *(const float4*)(base + (size_t)(cy1 * HO + cx0) * CO);
      c11[it] = *(const float4*)(base + (size_t)(cy1 * HO + cx1) * CO);
    }
  };

  auto combine = [&](int k, int buf) {
#pragma unroll
    for (int it = 0; it < 4; ++it) {
      int j = it * 256 + t;
      int q = j & 15, px = j >> 4;
      float w0 = sm.s.prm[k][px][0], w1 = sm.s.prm[k][px][1];
      float w2 = sm.s.prm[k][px][2], w3 = sm.s.prm[k][px][3];
      float vx = fmaf(w0, c00[it].x, fmaf(w1, c01[it].x, fmaf(w2, c10[it].x, w3 * c11[it].x)));
      float vy = fmaf(w0, c00[it].y, fmaf(w1, c01[it].y, fmaf(w2, c10[it].y, w3 * c11[it].y)));
      float vz = fmaf(w0, c00[it].z, fmaf(w1, c01[it].z, fmaf(w2, c10[it].z, w3 * c11[it].z)));
      float vw = fmaf(w0, c00[it].w, fmaf(w1, c01[it].w, fmaf(w2, c10[it].w, w3 * c11[it].w)));
      ushort4 st;
      st.x = f2bf(vx); st.y = f2bf(vy); st.z = f2bf(vz); st.w = f2bf(vw);
      *(ushort4*)&sm.s.Vt[buf][q >> 1][px][(q & 1) * 4] = st;
    }
  };

  f32x4 acc[4];
#pragma unroll
  for (int mt = 0; mt < 4; ++mt) acc[mt] = {0.f, 0.f, 0.f, 0.f};

  // preload first tap's B-frags (coalesced, L2-resident)
  uint4 bw0 = wf[(oq * 18 + 0) * 64 + lane];
  uint4 bw1 = wf[(oq * 18 + 1) * 64 + lane];
  uint4 bn0, bn1;

  issue(0);
  combine(0, 0);
  __syncthreads();

  union Cvt { uint4 u; short8 s; };
  int buf = 0;
#pragma unroll 1
  for (int k = 0; k < 9; ++k) {
    if (k < 8) {
      issue(k + 1);
      bn0 = wf[(oq * 18 + 2 * k + 2) * 64 + lane];
      bn1 = wf[(oq * 18 + 2 * k + 3) * 64 + lane];
    }
    // MFMA phase: 2 k-chunks x 4 M-tiles
#pragma unroll
    for (int kb2 = 0; kb2 < 2; ++kb2) {
      Cvt bfr; bfr.u = kb2 ? bw1 : bw0;
#pragma unroll
      for (int mt = 0; mt < 4; ++mt) {
        Cvt av;
        av.u = *(const uint4*)&sm.s.Vt[buf][kb2 * 4 + (lane >> 4)][mt * 16 + (lane & 15)][0];
        acc[mt] = __builtin_amdgcn_mfma_f32_16x16x32_bf16(av.s, bfr.s, acc[mt], 0, 0, 0);
      }
    }
    if (k < 8) combine(k + 1, buf ^ 1);
    __syncthreads();
    bw0 = bn0; bw1 = bn1;
    buf ^= 1;
  }

  // epilogue: transpose acc via padded LDS, coalesced store + bias + leaky relu
#pragma unroll
  for (int mt = 0; mt < 4; ++mt)
#pragma unroll
    for (int r = 0; r < 4; ++r)
      sm.accs[oq][lane & 15][mt * 16 + (lane >> 4) * 4 + r] = acc[mt][r];
  __syncthreads();

  const int y = tY + (lane >> 4), x = tX + (lane & 15);
  float* ob = out + (size_t)b * 2 * CO * HW + (size_t)y * HO + x;
#pragma unroll
  for (int ol = 0; ol < 16; ++ol) {
    int o = oq * 16 + ol;
    float v = sm.accs[oq][ol][lane] + bal[o];
    v = (v >= 0.f) ? v : 0.2f * v;                // leaky relu
    ob[(size_t)o * HW] = v;
  }
}

// ---------------- K4: copy low_feature into out channels 64..127 -----------------
__global__ void k_copy(const float* __restrict__ low, float* __restrict__ out) {
  int i = blockIdx.x * 256 + threadIdx.x;       // over B*CO*HW/4 float4s
  int b = i >> 18;                              // 262144 float4 per batch
  float4 v = ((const float4*)low)[i];
  ((float4*)out)[i + (b + 1) * 262144] = v;
}

extern "C" void kernel_launch(void* const* d_in, const int* in_sizes, int n_in,
                              void* d_out, int out_size, void* d_ws, size_t ws_size,
                              hipStream_t stream) {
  const float* high = (const float*)d_in[0];
  const float* low  = (const float*)d_in[1];
  const float* wup  = (const float*)d_in[2];
  const float* bup  = (const float*)d_in[3];
  const float* woff = (const float*)d_in[4];
  const float* boff = (const float*)d_in[5];
  const float* wal  = (const float*)d_in[6];
  const float* bal  = (const float*)d_in[7];
  float* out = (float*)d_out;
  float* ws  = (float*)d_ws;

  k_repack<<<dim3(288), dim3(256), 0, stream>>>(wup, woff, wal, ws);
  k_cvt<<<dim3(HF, B), dim3(256), 0, stream>>>(high, ws);
  k_up<<<dim3(4, 16, B * 4), dim3(256), 0, stream>>>(bup, ws);
  k_off<<<dim3(8, 8, B * 4), dim3(256), 0, stream>>>(low, boff, ws);
  k_dcn<<<dim3(8, 32, B), dim3(256), 0, stream>>>(bal, out, ws);
  k_copy<<<dim3(4096), dim3(256), 0, stream>>>(low, out);
}

// Round 6
// 100.647 us; speedup vs baseline: 6.9131x; 1.7225x over previous
//
#include <hip/hip_runtime.h>
#include <math.h>

namespace {
constexpr int B   = 4;
constexpr int CIN = 128;   // high channels
constexpr int CO  = 64;    // up / aligned channels
constexpr int HF  = 64;    // high H=W
constexpr int HO  = 128;   // up/out H=W
constexpr int HW  = HO * HO;   // 16384
constexpr int NOFF = 27;   // 18 offset + 9 mask channels

// workspace layout (float units)
constexpr size_t UPB  = 0;                               // bf16 [B][HO][HO][CO] up, NHWC
constexpr size_t LOB  = UPB + (size_t)B * HW * CO / 2;   // bf16 [B][HO][HO][CO] low, NHWC
constexpr size_t FOO  = LOB + (size_t)B * HW * CO / 2;   // fp32 [B][27][HW] offsets+mask;
                                                         // early: bf16 [B][HF][HF][CIN] high
constexpr size_t WFRG = FOO + (size_t)B * NOFF * HW;           // k_dcn B-frags [4][18][64][8]
constexpr size_t WFUP = WFRG + (size_t)(4 * 18 * 64 * 8) / 2;  // k_up B-frags [9][4][4][64][8]
constexpr size_t WFOF = WFUP + (size_t)(9 * 4 * 4 * 64 * 8) / 2; // k_off B-frags [9][4][2][64][8]
}

using short8 = __attribute__((ext_vector_type(8))) short;
using f32x4  = __attribute__((ext_vector_type(4))) float;

__device__ __forceinline__ unsigned short f2bf(float f) {
  unsigned u = __float_as_uint(f);
  u += 0x7fffu + ((u >> 16) & 1u);      // RNE
  return (unsigned short)(u >> 16);
}

// ---------------- weight repack into bf16 MFMA B-fragments ------------------------
__global__ void k_repack(const float* __restrict__ wup, const float* __restrict__ woff,
                         const float* __restrict__ wal, float* __restrict__ ws) {
  int i = blockIdx.x * 256 + threadIdx.x;
  if (i < 4 * 18 * 64 * 8) {              // k_dcn: [w][kb][lane][j]
    int j = i & 7; int t2 = i >> 3;
    int lane = t2 & 63; int t3 = t2 >> 6;
    int kb = t3 % 18; int w = t3 / 18;
    int tap = kb >> 1;
    int c = (kb & 1) * 32 + ((lane >> 4) << 3) + j;
    int o = (w << 4) + (lane & 15);
    unsigned short* wfrag = (unsigned short*)(ws + WFRG);
    wfrag[i] = f2bf(wal[((size_t)o * CO + c) * 9 + tap]);
  }
  if (i < 9 * 4 * 4 * 64 * 8) {           // k_up: [rr][ch][w][lane][j]
    int j = i & 7; int lane = (i >> 3) & 63; int w = (i >> 9) & 3;
    int ch = (i >> 11) & 3; int rr = i >> 13;
    int c = ch * 32 + ((lane >> 4) << 3) + j;
    int o = w * 16 + (lane & 15);
    unsigned short* wfup = (unsigned short*)(ws + WFUP);
    wfup[i] = f2bf(wup[((size_t)c * CO + o) * 9 + rr]);
  }
  if (i < 9 * 4 * 2 * 64 * 8) {           // k_off: [tap][kc][nt][lane][j]
    int j = i & 7; int lane = (i >> 3) & 63; int nt = (i >> 9) & 1;
    int kc = (i >> 10) & 3; int tap = i >> 12;
    int c = kc * 32 + ((lane >> 4) << 3) + j;     // virtual in-ch: 0..63 up, 64..127 low
    int o = nt * 16 + (lane & 15);
    float v = 0.f;
    if (o < NOFF) v = woff[(((size_t)o * 2 * CO + c) * 3 + tap / 3) * 3 + (tap % 3)];
    unsigned short* wfo = (unsigned short*)(ws + WFOF);
    wfo[i] = f2bf(v);
  }
}

// ---------------- K0a: high fp32 NCHW -> bf16 NHWC (into FOO region) --------------
__global__ __launch_bounds__(256) void k_cvt(const float* __restrict__ high,
                                             float* __restrict__ ws) {
  __shared__ unsigned short tl[32][66];
  unsigned short* hbf = (unsigned short*)(ws + FOO);
  const int t = threadIdx.x;
  const int y = blockIdx.x, b = blockIdx.y;
  const int x = t & 63, clb = t >> 6;

  for (int c0 = 0; c0 < CIN; c0 += 32) {
    __syncthreads();
#pragma unroll
    for (int k = 0; k < 8; ++k) {
      int cl = clb * 8 + k;
      float v = high[(((size_t)b * CIN + c0 + cl) * HF + y) * HF + x];
      tl[cl][x] = f2bf(v);
    }
    __syncthreads();
    int px = t >> 2, cg = t & 3;
    ushort4 a, bb;
    a.x = tl[cg * 8 + 0][px]; a.y = tl[cg * 8 + 1][px];
    a.z = tl[cg * 8 + 2][px]; a.w = tl[cg * 8 + 3][px];
    bb.x = tl[cg * 8 + 4][px]; bb.y = tl[cg * 8 + 5][px];
    bb.z = tl[cg * 8 + 6][px]; bb.w = tl[cg * 8 + 7][px];
    unsigned short* dst = hbf + (((size_t)b * HF + y) * HF + px) * CIN + c0 + cg * 8;
    *(ushort4*)(dst) = a;
    *(ushort4*)(dst + 4) = bb;
  }
}

// ---------------- K0b: low fp32 NCHW -> bf16 NHWC (LOB) ---------------------------
__global__ __launch_bounds__(256) void k_cvt2(const float* __restrict__ low,
                                              float* __restrict__ ws) {
  __shared__ unsigned short tl[64][130];
  unsigned short* lob = (unsigned short*)(ws + LOB);
  const int t = threadIdx.x;
  const int y = blockIdx.x, b = blockIdx.y;

#pragma unroll
  for (int it = 0; it < 8; ++it) {        // 2048 float4 over 256 threads
    int i = it * 256 + t;
    int c = i >> 5, xi = (i & 31) * 4;
    float4 v = *(const float4*)(low + (((size_t)b * CO + c) * HO + y) * HO + xi);
    tl[c][xi + 0] = f2bf(v.x); tl[c][xi + 1] = f2bf(v.y);
    tl[c][xi + 2] = f2bf(v.z); tl[c][xi + 3] = f2bf(v.w);
  }
  __syncthreads();
#pragma unroll
  for (int it = 0; it < 4; ++it) {        // 128 px x 8 cgroups
    int i = it * 256 + t;
    int x = i >> 3, cg = i & 7;
    unsigned rw[4];
#pragma unroll
    for (int p = 0; p < 4; ++p)
      rw[p] = (unsigned)tl[cg * 8 + 2 * p][x] | ((unsigned)tl[cg * 8 + 2 * p + 1][x] << 16);
    *(uint4*)(lob + (((size_t)b * HO + y) * HO + x) * CO + cg * 8) =
        make_uint4(rw[0], rw[1], rw[2], rw[3]);
  }
}

// ---------------- K1: transposed conv as per-parity MFMA GEMM, bf16 NHWC out ------
union SmemUp {
  unsigned short At[2][4][85][8];       // [buf][cg][5*17 px][8ch] bf16
  float accs[4][16][65];                // epilogue transpose (pad 65)
};

__global__ __launch_bounds__(256) void k_up(const float* __restrict__ bup,
                                            float* __restrict__ ws) {
  __shared__ SmemUp sm;
  const unsigned short* hbf = (const unsigned short*)(ws + FOO);
  const uint4* wfu = (const uint4*)(ws + WFUP);
  unsigned short* upb = (unsigned short*)(ws + UPB);

  const int t    = threadIdx.x;
  const int lane = t & 63;
  const int oq   = __builtin_amdgcn_readfirstlane(t >> 6);
  const int z    = blockIdx.z;
  const int b    = z >> 2;
  const int pyv  = (z >> 1) & 1, pxv = z & 1;
  const int ty   = blockIdx.y * 4;
  const int tx   = blockIdx.x * 16;
  const int nty  = pyv + 1, ntx = pxv + 1;

  uint4 s0, s1;
  const int pxA = t >> 2, cgA = t & 3;
  const int i2 = t + 256, pxB = i2 >> 2, cgB = i2 & 3;

  auto load_chunk = [&](int c0) {
    {
      int gy = ty + pxA / 17, gx = tx + pxA % 17;
      s0 = make_uint4(0, 0, 0, 0);
      if (gy < HF && gx < HF)
        s0 = *(const uint4*)(hbf + (((size_t)b * HF + gy) * HF + gx) * CIN + c0 + cgA * 8);
    }
    s1 = make_uint4(0, 0, 0, 0);
    if (pxB < 85) {
      int gy = ty + pxB / 17, gx = tx + pxB % 17;
      if (gy < HF && gx < HF)
        s1 = *(const uint4*)(hbf + (((size_t)b * HF + gy) * HF + gx) * CIN + c0 + cgB * 8);
    }
  };
  auto write_chunk = [&](int buf) {
    *(uint4*)&sm.At[buf][cgA][pxA][0] = s0;
    if (pxB < 85) *(uint4*)&sm.At[buf][cgB][pxB][0] = s1;
  };

  f32x4 acc[4];
#pragma unroll
  for (int mt = 0; mt < 4; ++mt) acc[mt] = {0.f, 0.f, 0.f, 0.f};

  load_chunk(0);
  write_chunk(0);
  __syncthreads();

  union Cvt { uint4 u; short8 s; };
  int buf = 0;
#pragma unroll 1
  for (int ch = 0; ch < 4; ++ch) {
    if (ch < 3) load_chunk((ch + 1) * 32);
#pragma unroll
    for (int ti = 0; ti < 2; ++ti) {
      if (ti < nty) {
#pragma unroll
        for (int tj = 0; tj < 2; ++tj) {
          if (tj < ntx) {
            int ryA = pyv ? 2 - 2 * ti : 1;
            int rxA = pxv ? 2 - 2 * tj : 1;
            int rr = ryA * 3 + rxA;
            Cvt bw; bw.u = wfu[(((size_t)rr * 4 + ch) * 4 + oq) * 64 + lane];
#pragma unroll
            for (int mt = 0; mt < 4; ++mt) {
              Cvt av;
              av.u = *(const uint4*)&sm.At[buf][lane >> 4][(mt + ti) * 17 + (lane & 15) + tj][0];
              acc[mt] = __builtin_amdgcn_mfma_f32_16x16x32_bf16(av.s, bw.s, acc[mt], 0, 0, 0);
            }
          }
        }
      }
    }
    if (ch < 3) write_chunk(buf ^ 1);
    __syncthreads();
    buf ^= 1;
  }

  // epilogue: transpose via padded LDS, bf16 NHWC stores + bias
#pragma unroll
  for (int mt = 0; mt < 4; ++mt)
#pragma unroll
    for (int r = 0; r < 4; ++r)
      sm.accs[oq][lane & 15][mt * 16 + (lane >> 4) * 4 + r] = acc[mt][r];
  __syncthreads();

  const int yo = 2 * (ty + (lane >> 4)) + pyv;
  const int xo = 2 * (tx + (lane & 15)) + pxv;
  unsigned short* dst = upb + (((size_t)b * HO + yo) * HO + xo) * CO + oq * 16;
  unsigned rw[8];
#pragma unroll
  for (int p = 0; p < 8; ++p) {
    float v0 = sm.accs[oq][2 * p][lane] + bup[oq * 16 + 2 * p];
    float v1 = sm.accs[oq][2 * p + 1][lane] + bup[oq * 16 + 2 * p + 1];
    rw[p] = (unsigned)f2bf(v0) | ((unsigned)f2bf(v1) << 16);
  }
  *(uint4*)dst = make_uint4(rw[0], rw[1], rw[2], rw[3]);
  *(uint4*)(dst + 8) = make_uint4(rw[4], rw[5], rw[6], rw[7]);
}

// ---------------- K2: 3x3 conv (MFMA) over concat(up,low) bf16 NHWC -> fo ---------
// block 256 = 4 waves: wave = (mh = px-half, nt = out-16-group). Tile 64 px (16x4).
union SmemOff {
  unsigned short in[16][108][8];        // [cg][6*18 halo px][8ch] bf16 = 27648 B
  float accs[32][66];                   // [oc][px+pad]
};

__global__ __launch_bounds__(256) void k_off(const float* __restrict__ boff,
                                             float* __restrict__ ws) {
  __shared__ SmemOff sm;
  const unsigned short* upb = (const unsigned short*)(ws + UPB);
  const unsigned short* lob = (const unsigned short*)(ws + LOB);
  const uint4* wfo = (const uint4*)(ws + WFOF);
  float* fo = ws + FOO;

  const int t = threadIdx.x;
  const int lane = t & 63;
  const int w = __builtin_amdgcn_readfirstlane(t >> 6);
  const int mh = w >> 1, nt = w & 1;
  const int b = blockIdx.z;
  const int tY = blockIdx.y * 4, tX = blockIdx.x * 16;

  for (int i = t; i < 16 * 108; i += 256) {
    int px = i >> 4, cg = i & 15;
    int gy = tY - 1 + px / 18, gx = tX - 1 + px % 18;
    uint4 v = make_uint4(0, 0, 0, 0);
    if (gy >= 0 && gy < HO && gx >= 0 && gx < HO) {
      const unsigned short* src =
          (cg < 8 ? upb : lob) + (((size_t)b * HO + gy) * HO + gx) * CO + (cg & 7) * 8;
      v = *(const uint4*)src;
    }
    *(uint4*)&sm.in[cg][px][0] = v;
  }
  __syncthreads();

  union Cvt { uint4 u; short8 s; };
  f32x4 acc[2];
  acc[0] = {0.f, 0.f, 0.f, 0.f}; acc[1] = {0.f, 0.f, 0.f, 0.f};
#pragma unroll 1
  for (int tap = 0; tap < 9; ++tap) {
    int ky = tap / 3, kx = tap % 3;
#pragma unroll
    for (int kc = 0; kc < 4; ++kc) {
      Cvt bw; bw.u = wfo[(((size_t)tap * 4 + kc) * 2 + nt) * 64 + lane];
#pragma unroll
      for (int mt = 0; mt < 2; ++mt) {
        int sy = mh * 2 + mt;
        Cvt av;
        av.u = *(const uint4*)&sm.in[kc * 4 + (lane >> 4)][(sy + ky) * 18 + (lane & 15) + kx][0];
        acc[mt] = __builtin_amdgcn_mfma_f32_16x16x32_bf16(av.s, bw.s, acc[mt], 0, 0, 0);
      }
    }
  }
  __syncthreads();

#pragma unroll
  for (int mt = 0; mt < 2; ++mt)
#pragma unroll
    for (int r = 0; r < 4; ++r)
      sm.accs[nt * 16 + (lane & 15)][mh * 32 + mt * 16 + (lane >> 4) * 4 + r] = acc[mt][r];
  __syncthreads();

  for (int i = t; i < NOFF * 64; i += 256) {
    int oc = i >> 6, px = i & 63;
    float v = sm.accs[oc][px] + boff[oc];
    if (oc >= 18) v = 2.f / (1.f + expf(-v));     // mask = 2*sigmoid
    fo[(((size_t)b * NOFF + oc) * HO + tY + (px >> 4)) * HO + tX + (px & 15)] = v;
  }
}

// ---------------- K3: modulated deformable conv (MFMA GEMM) + leaky relu ----------
union SmemU {
  struct {
    float prm[9][64][5];                  // bilinear weights + packed corners
    unsigned short Vt[2][8][64][8];       // [buf][kchunk][px][8ch] bf16
  } s;
  float accs[4][16][65];                  // epilogue transpose (pad 65)
};

__global__ __launch_bounds__(256) void k_dcn(const float* __restrict__ bal,
                                             float* __restrict__ out,
                                             const float* __restrict__ ws) {
  __shared__ SmemU sm;
  const unsigned short* upb = (const unsigned short*)(ws + UPB);
  const float* fo  = ws + FOO;
  const uint4* wf  = (const uint4*)(ws + WFRG);

  const int t    = threadIdx.x;
  const int lane = t & 63;
  const int oq   = __builtin_amdgcn_readfirstlane(t >> 6);
  const int b    = blockIdx.z;
  const int tY   = blockIdx.y * 4, tX = blockIdx.x * 16;
  const unsigned short* upB = upb + (size_t)b * HW * CO;

  for (int i = t; i < 9 * 64; i += 256) {
    int k = i >> 6, px = i & 63;
    int y = tY + (px >> 4), x = tX + (px & 15);
    const float* foP = fo + (size_t)b * NOFF * HW + (size_t)y * HO + x;
    float offy = foP[(size_t)(2 * k) * HW];
    float offx = foP[(size_t)(2 * k + 1) * HW];
    float m    = foP[(size_t)(18 + k) * HW];
    float pyf = offy + (float)(y - 1 + k / 3);
    float pxf = offx + (float)(x - 1 + k % 3);
    float y0f = floorf(pyf), x0f = floorf(pxf);
    float wy = pyf - y0f, wx = pxf - x0f;
    int y0 = (int)y0f, x0 = (int)x0f;
    int y1 = y0 + 1, x1 = x0 + 1;
    float vy0 = (y0 >= 0 && y0 < HO) ? m : 0.f;
    float vy1 = (y1 >= 0 && y1 < HO) ? m : 0.f;
    float vx0 = (x0 >= 0 && x0 < HO) ? 1.f : 0.f;
    float vx1 = (x1 >= 0 && x1 < HO) ? 1.f : 0.f;
    sm.s.prm[k][px][0] = (1.f - wy) * (1.f - wx) * vy0 * vx0;
    sm.s.prm[k][px][1] = (1.f - wy) * wx * vy0 * vx1;
    sm.s.prm[k][px][2] = wy * (1.f - wx) * vy1 * vx0;
    sm.s.prm[k][px][3] = wy * wx * vy1 * vx1;
    int cy0 = min(max(y0, 0), HO - 1), cy1 = min(max(y1, 0), HO - 1);
    int cx0 = min(max(x0, 0), HO - 1), cx1 = min(max(x1, 0), HO - 1);
    unsigned pc = (unsigned)cy0 | ((unsigned)cy1 << 8) |
                  ((unsigned)cx0 << 16) | ((unsigned)cx1 << 24);
    sm.s.prm[k][px][4] = __uint_as_float(pc);
  }
  __syncthreads();

  uint4 u00[2], u01[2], u10[2], u11[2];

  auto issue = [&](int k) {        // bf16 gathers: 8 lanes x 16B = 128B runs per corner
#pragma unroll
    for (int it = 0; it < 2; ++it) {
      int j = it * 256 + t;
      int q = j & 7, px = j >> 3;
      unsigned pc = __float_as_uint(sm.s.prm[k][px][4]);
      int cy0 = pc & 255, cy1 = (pc >> 8) & 255, cx0 = (pc >> 16) & 255, cx1 = pc >> 24;
      const unsigned short* base = upB + q * 8;
      u00[it] = *(const uint4*)(base + (size_t)(cy0 * HO + cx0) * CO);
      u01[it] = *(const uint4*)(base + (size_t)(cy0 * HO + cx1) * CO);
      u10[it] = *(const uint4*)(base + (size_t)(cy1 * HO + cx0) * CO);
      u11[it] = *(const uint4*)(base + (size_t)(cy1 * HO + cx1) * CO);
    }
  };

  auto combine = [&](int k, int buf) {
#pragma unroll
    for (int it = 0; it < 2; ++it) {
      int j = it * 256 + t;
      int q = j & 7, px = j >> 3;
      float w0 = sm.s.prm[k][px][0], w1 = sm.s.prm[k][px][1];
      float w2 = sm.s.prm[k][px][2], w3 = sm.s.prm[k][px][3];
      unsigned a0[4] = {u00[it].x, u00[it].y, u00[it].z, u00[it].w};
      unsigned a1[4] = {u01[it].x, u01[it].y, u01[it].z, u01[it].w};
      unsigned a2[4] = {u10[it].x, u10[it].y, u10[it].z, u10[it].w};
      unsigned a3[4] = {u11[it].x, u11[it].y, u11[it].z, u11[it].w};
      unsigned rw[4];
#pragma unroll
      for (int p = 0; p < 4; ++p) {
        float l0 = __uint_as_float(a0[p] << 16), h0 = __uint_as_float(a0[p] & 0xffff0000u);
        float l1 = __uint_as_float(a1[p] << 16), h1 = __uint_as_float(a1[p] & 0xffff0000u);
        float l2 = __uint_as_float(a2[p] << 16), h2 = __uint_as_float(a2[p] & 0xffff0000u);
        float l3 = __uint_as_float(a3[p] << 16), h3 = __uint_as_float(a3[p] & 0xffff0000u);
        float vlo = fmaf(w0, l0, fmaf(w1, l1, fmaf(w2, l2, w3 * l3)));
        float vhi = fmaf(w0, h0, fmaf(w1, h1, fmaf(w2, h2, w3 * h3)));
        rw[p] = (unsigned)f2bf(vlo) | ((unsigned)f2bf(vhi) << 16);
      }
      *(uint4*)&sm.s.Vt[buf][q][px][0] = make_uint4(rw[0], rw[1], rw[2], rw[3]);
    }
  };

  f32x4 acc[4];
#pragma unroll
  for (int mt = 0; mt < 4; ++mt) acc[mt] = {0.f, 0.f, 0.f, 0.f};

  uint4 bw0 = wf[(oq * 18 + 0) * 64 + lane];
  uint4 bw1 = wf[(oq * 18 + 1) * 64 + lane];
  uint4 bn0, bn1;

  issue(0);
  combine(0, 0);
  __syncthreads();

  union Cvt { uint4 u; short8 s; };
  int buf = 0;
#pragma unroll 1
  for (int k = 0; k < 9; ++k) {
    if (k < 8) {
      issue(k + 1);
      bn0 = wf[(oq * 18 + 2 * k + 2) * 64 + lane];
      bn1 = wf[(oq * 18 + 2 * k + 3) * 64 + lane];
    }
#pragma unroll
    for (int kb2 = 0; kb2 < 2; ++kb2) {
      Cvt bfr; bfr.u = kb2 ? bw1 : bw0;
#pragma unroll
      for (int mt = 0; mt < 4; ++mt) {
        Cvt av;
        av.u = *(const uint4*)&sm.s.Vt[buf][kb2 * 4 + (lane >> 4)][mt * 16 + (lane & 15)][0];
        acc[mt] = __builtin_amdgcn_mfma_f32_16x16x32_bf16(av.s, bfr.s, acc[mt], 0, 0, 0);
      }
    }
    if (k < 8) combine(k + 1, buf ^ 1);
    __syncthreads();
    bw0 = bn0; bw1 = bn1;
    buf ^= 1;
  }

#pragma unroll
  for (int mt = 0; mt < 4; ++mt)
#pragma unroll
    for (int r = 0; r < 4; ++r)
      sm.accs[oq][lane & 15][mt * 16 + (lane >> 4) * 4 + r] = acc[mt][r];
  __syncthreads();

  const int y = tY + (lane >> 4), x = tX + (lane & 15);
  float* ob = out + (size_t)b * 2 * CO * HW + (size_t)y * HO + x;
#pragma unroll
  for (int ol = 0; ol < 16; ++ol) {
    int o = oq * 16 + ol;
    float v = sm.accs[oq][ol][lane] + bal[o];
    v = (v >= 0.f) ? v : 0.2f * v;                // leaky relu
    ob[(size_t)o * HW] = v;
  }
}

// ---------------- K4: copy low_feature into out channels 64..127 -----------------
__global__ void k_copy(const float* __restrict__ low, float* __restrict__ out) {
  int i = blockIdx.x * 256 + threadIdx.x;       // over B*CO*HW/4 float4s
  int b = i >> 18;                              // 262144 float4 per batch
  float4 v = ((const float4*)low)[i];
  ((float4*)out)[i + (b + 1) * 262144] = v;
}

extern "C" void kernel_launch(void* const* d_in, const int* in_sizes, int n_in,
                              void* d_out, int out_size, void* d_ws, size_t ws_size,
                              hipStream_t stream) {
  const float* high = (const float*)d_in[0];
  const float* low  = (const float*)d_in[1];
  const float* wup  = (const float*)d_in[2];
  const float* bup  = (const float*)d_in[3];
  const float* woff = (const float*)d_in[4];
  const float* boff = (const float*)d_in[5];
  const float* wal  = (const float*)d_in[6];
  const float* bal  = (const float*)d_in[7];
  float* out = (float*)d_out;
  float* ws  = (float*)d_ws;

  k_repack<<<dim3(288), dim3(256), 0, stream>>>(wup, woff, wal, ws);
  k_cvt<<<dim3(HF, B), dim3(256), 0, stream>>>(high, ws);
  k_cvt2<<<dim3(HO, B), dim3(256), 0, stream>>>(low, ws);
  k_up<<<dim3(4, 16, B * 4), dim3(256), 0, stream>>>(bup, ws);
  k_off<<<dim3(8, 32, B), dim3(256), 0, stream>>>(boff, ws);
  k_dcn<<<dim3(8, 32, B), dim3(256), 0, stream>>>(bal, out, ws);
  k_copy<<<dim3(4096), dim3(256), 0, stream>>>(low, out);
}

// Round 7
// 71.283 us; speedup vs baseline: 9.7609x; 1.4119x over previous
//
#include <hip/hip_runtime.h>
#include <math.h>

namespace {
constexpr int B   = 4;
constexpr int CIN = 128;   // high channels
constexpr int CO  = 64;    // up / aligned channels
constexpr int HF  = 64;    // high H=W
constexpr int HO  = 128;   // up/out H=W
constexpr int HW  = HO * HO;   // 16384
constexpr int NOFF = 27;   // 18 offset + 9 mask channels

// workspace layout (float units)
constexpr size_t UPB  = 0;                               // bf16 [B][HO][HO][CO] up, NHWC
constexpr size_t LOB  = UPB + (size_t)B * HW * CO / 2;   // bf16 [B][HO][HO][CO] low, NHWC
constexpr size_t HBF  = LOB + (size_t)B * HW * CO / 2;   // bf16 [B][HF][HF][CIN] high, NHWC
constexpr size_t WFRG = HBF + (size_t)B * HF * HF * CIN / 2;   // k_dcn B-frags [4][18][64][8]
constexpr size_t WFUP = WFRG + (size_t)(4 * 18 * 64 * 8) / 2;  // k_up B-frags [9][4][4][64][8]
constexpr size_t WFOF = WFUP + (size_t)(9 * 4 * 4 * 64 * 8) / 2; // k_off B-frags [9][4][2][64][8]
}

using short8 = __attribute__((ext_vector_type(8))) short;
using f32x4  = __attribute__((ext_vector_type(4))) float;

__device__ __forceinline__ unsigned short f2bf(float f) {
  unsigned u = __float_as_uint(f);
  u += 0x7fffu + ((u >> 16) & 1u);      // RNE
  return (unsigned short)(u >> 16);
}

// ---------------- weight repack into bf16 MFMA B-fragments ------------------------
__global__ void k_repack(const float* __restrict__ wup, const float* __restrict__ woff,
                         const float* __restrict__ wal, float* __restrict__ ws) {
  int i = blockIdx.x * 256 + threadIdx.x;
  if (i < 4 * 18 * 64 * 8) {              // k_dcn: [w][kb][lane][j]
    int j = i & 7; int t2 = i >> 3;
    int lane = t2 & 63; int t3 = t2 >> 6;
    int kb = t3 % 18; int w = t3 / 18;
    int tap = kb >> 1;
    int c = (kb & 1) * 32 + ((lane >> 4) << 3) + j;
    int o = (w << 4) + (lane & 15);
    unsigned short* wfrag = (unsigned short*)(ws + WFRG);
    wfrag[i] = f2bf(wal[((size_t)o * CO + c) * 9 + tap]);
  }
  if (i < 9 * 4 * 4 * 64 * 8) {           // k_up: [rr][ch][w][lane][j]
    int j = i & 7; int lane = (i >> 3) & 63; int w = (i >> 9) & 3;
    int ch = (i >> 11) & 3; int rr = i >> 13;
    int c = ch * 32 + ((lane >> 4) << 3) + j;
    int o = w * 16 + (lane & 15);
    unsigned short* wfup = (unsigned short*)(ws + WFUP);
    wfup[i] = f2bf(wup[((size_t)c * CO + o) * 9 + rr]);
  }
  if (i < 9 * 4 * 2 * 64 * 8) {           // k_off: [tap][kc][nt][lane][j]
    int j = i & 7; int lane = (i >> 3) & 63; int nt = (i >> 9) & 1;
    int kc = (i >> 10) & 3; int tap = i >> 12;
    int c = kc * 32 + ((lane >> 4) << 3) + j;     // virtual in-ch: 0..63 up, 64..127 low
    int o = nt * 16 + (lane & 15);
    float v = 0.f;
    if (o < NOFF) v = woff[(((size_t)o * 2 * CO + c) * 3 + tap / 3) * 3 + (tap % 3)];
    unsigned short* wfo = (unsigned short*)(ws + WFOF);
    wfo[i] = f2bf(v);
  }
}

// ---------------- K0a: high fp32 NCHW -> bf16 NHWC --------------------------------
__global__ __launch_bounds__(256) void k_cvt(const float* __restrict__ high,
                                             float* __restrict__ ws) {
  __shared__ unsigned short tl[32][66];
  unsigned short* hbf = (unsigned short*)(ws + HBF);
  const int t = threadIdx.x;
  const int y = blockIdx.x, b = blockIdx.y;
  const int x = t & 63, clb = t >> 6;

  for (int c0 = 0; c0 < CIN; c0 += 32) {
    __syncthreads();
#pragma unroll
    for (int k = 0; k < 8; ++k) {
      int cl = clb * 8 + k;
      float v = high[(((size_t)b * CIN + c0 + cl) * HF + y) * HF + x];
      tl[cl][x] = f2bf(v);
    }
    __syncthreads();
    int px = t >> 2, cg = t & 3;
    ushort4 a, bb;
    a.x = tl[cg * 8 + 0][px]; a.y = tl[cg * 8 + 1][px];
    a.z = tl[cg * 8 + 2][px]; a.w = tl[cg * 8 + 3][px];
    bb.x = tl[cg * 8 + 4][px]; bb.y = tl[cg * 8 + 5][px];
    bb.z = tl[cg * 8 + 6][px]; bb.w = tl[cg * 8 + 7][px];
    unsigned short* dst = hbf + (((size_t)b * HF + y) * HF + px) * CIN + c0 + cg * 8;
    *(ushort4*)(dst) = a;
    *(ushort4*)(dst + 4) = bb;
  }
}

// ---------------- K0b: low fp32 NCHW -> bf16 NHWC + fp32 copy into out ------------
__global__ __launch_bounds__(256) void k_cvt2(const float* __restrict__ low,
                                              float* __restrict__ out,
                                              float* __restrict__ ws) {
  __shared__ unsigned short tl[64][130];
  unsigned short* lob = (unsigned short*)(ws + LOB);
  const int t = threadIdx.x;
  const int y = blockIdx.x, b = blockIdx.y;

#pragma unroll
  for (int it = 0; it < 8; ++it) {        // 2048 float4 over 256 threads
    int i = it * 256 + t;
    int c = i >> 5, xi = (i & 31) * 4;
    float4 v = *(const float4*)(low + (((size_t)b * CO + c) * HO + y) * HO + xi);
    // fused copy: out channels 64..127 = low (fp32 NCHW)
    *(float4*)(out + (((size_t)b * 2 * CO + CO + c) * HO + y) * HO + xi) = v;
    tl[c][xi + 0] = f2bf(v.x); tl[c][xi + 1] = f2bf(v.y);
    tl[c][xi + 2] = f2bf(v.z); tl[c][xi + 3] = f2bf(v.w);
  }
  __syncthreads();
#pragma unroll
  for (int it = 0; it < 4; ++it) {        // 128 px x 8 cgroups
    int i = it * 256 + t;
    int x = i >> 3, cg = i & 7;
    unsigned rw[4];
#pragma unroll
    for (int p = 0; p < 4; ++p)
      rw[p] = (unsigned)tl[cg * 8 + 2 * p][x] | ((unsigned)tl[cg * 8 + 2 * p + 1][x] << 16);
    *(uint4*)(lob + (((size_t)b * HO + y) * HO + x) * CO + cg * 8) =
        make_uint4(rw[0], rw[1], rw[2], rw[3]);
  }
}

// ---------------- K1: transposed conv as per-parity MFMA GEMM, bf16 NHWC out ------
union SmemUp {
  unsigned short At[2][4][85][8];       // [buf][cg][5*17 px][8ch] bf16
  float accs[4][16][65];                // epilogue transpose (pad 65)
};

__global__ __launch_bounds__(256) void k_up(const float* __restrict__ bup,
                                            float* __restrict__ ws) {
  __shared__ SmemUp sm;
  const unsigned short* hbf = (const unsigned short*)(ws + HBF);
  const uint4* wfu = (const uint4*)(ws + WFUP);
  unsigned short* upb = (unsigned short*)(ws + UPB);

  const int t    = threadIdx.x;
  const int lane = t & 63;
  const int oq   = __builtin_amdgcn_readfirstlane(t >> 6);
  const int z    = blockIdx.z;
  const int b    = z >> 2;
  const int pyv  = (z >> 1) & 1, pxv = z & 1;
  const int ty   = blockIdx.y * 4;
  const int tx   = blockIdx.x * 16;
  const int nty  = pyv + 1, ntx = pxv + 1;

  uint4 s0, s1;
  const int pxA = t >> 2, cgA = t & 3;
  const int i2 = t + 256, pxB = i2 >> 2, cgB = i2 & 3;

  auto load_chunk = [&](int c0) {
    {
      int gy = ty + pxA / 17, gx = tx + pxA % 17;
      s0 = make_uint4(0, 0, 0, 0);
      if (gy < HF && gx < HF)
        s0 = *(const uint4*)(hbf + (((size_t)b * HF + gy) * HF + gx) * CIN + c0 + cgA * 8);
    }
    s1 = make_uint4(0, 0, 0, 0);
    if (pxB < 85) {
      int gy = ty + pxB / 17, gx = tx + pxB % 17;
      if (gy < HF && gx < HF)
        s1 = *(const uint4*)(hbf + (((size_t)b * HF + gy) * HF + gx) * CIN + c0 + cgB * 8);
    }
  };
  auto write_chunk = [&](int buf) {
    *(uint4*)&sm.At[buf][cgA][pxA][0] = s0;
    if (pxB < 85) *(uint4*)&sm.At[buf][cgB][pxB][0] = s1;
  };

  f32x4 acc[4];
#pragma unroll
  for (int mt = 0; mt < 4; ++mt) acc[mt] = {0.f, 0.f, 0.f, 0.f};

  load_chunk(0);
  write_chunk(0);
  __syncthreads();

  union Cvt { uint4 u; short8 s; };
  int buf = 0;
#pragma unroll 1
  for (int ch = 0; ch < 4; ++ch) {
    if (ch < 3) load_chunk((ch + 1) * 32);
#pragma unroll
    for (int ti = 0; ti < 2; ++ti) {
      if (ti < nty) {
#pragma unroll
        for (int tj = 0; tj < 2; ++tj) {
          if (tj < ntx) {
            int ryA = pyv ? 2 - 2 * ti : 1;
            int rxA = pxv ? 2 - 2 * tj : 1;
            int rr = ryA * 3 + rxA;
            Cvt bw; bw.u = wfu[(((size_t)rr * 4 + ch) * 4 + oq) * 64 + lane];
#pragma unroll
            for (int mt = 0; mt < 4; ++mt) {
              Cvt av;
              av.u = *(const uint4*)&sm.At[buf][lane >> 4][(mt + ti) * 17 + (lane & 15) + tj][0];
              acc[mt] = __builtin_amdgcn_mfma_f32_16x16x32_bf16(av.s, bw.s, acc[mt], 0, 0, 0);
            }
          }
        }
      }
    }
    if (ch < 3) write_chunk(buf ^ 1);
    __syncthreads();
    buf ^= 1;
  }

  // epilogue: transpose via padded LDS, bf16 NHWC stores + bias
#pragma unroll
  for (int mt = 0; mt < 4; ++mt)
#pragma unroll
    for (int r = 0; r < 4; ++r)
      sm.accs[oq][lane & 15][mt * 16 + (lane >> 4) * 4 + r] = acc[mt][r];
  __syncthreads();

  const int yo = 2 * (ty + (lane >> 4)) + pyv;
  const int xo = 2 * (tx + (lane & 15)) + pxv;
  unsigned short* dst = upb + (((size_t)b * HO + yo) * HO + xo) * CO + oq * 16;
  unsigned rw[8];
#pragma unroll
  for (int p = 0; p < 8; ++p) {
    float v0 = sm.accs[oq][2 * p][lane] + bup[oq * 16 + 2 * p];
    float v1 = sm.accs[oq][2 * p + 1][lane] + bup[oq * 16 + 2 * p + 1];
    rw[p] = (unsigned)f2bf(v0) | ((unsigned)f2bf(v1) << 16);
  }
  *(uint4*)dst = make_uint4(rw[0], rw[1], rw[2], rw[3]);
  *(uint4*)(dst + 8) = make_uint4(rw[4], rw[5], rw[6], rw[7]);
}

// ---------------- K2: FUSED offset-conv (MFMA) + modulated deformable conv --------
// Tile 64 px (16x4), grid (8,32,B). fo never leaves LDS.
// LDS arena (36352 B), phase-overlaid:
//   phase1: in[16][108][8] bf16 @0 (27648 B)
//   phase2: fo_raw[32][66] f32 @0 (8448 B) + prm[9][64][5] f32 @8448 (11520 B)
//   phase3: prm (kept) + Vt[2][8][64][8] bf16 @19968 (16384 B)
//   phase4: accs[4][16][65] f32 @0 (16640 B)
__global__ __launch_bounds__(256) void k_offdcn(const float* __restrict__ boff,
                                                const float* __restrict__ bal,
                                                float* __restrict__ out,
                                                const float* __restrict__ ws) {
  __shared__ float smem[9088];          // 36352 B
  unsigned short* us_in = (unsigned short*)smem;
  float* fo_raw = smem;                                   // [32][66]
  float* prm = smem + 2112;                               // [9][64][5]
  unsigned short* us_vt = (unsigned short*)(smem + 4992); // [2][8][64][8]

  const unsigned short* upb = (const unsigned short*)(ws + UPB);
  const unsigned short* lob = (const unsigned short*)(ws + LOB);
  const uint4* wfo = (const uint4*)(ws + WFOF);
  const uint4* wf  = (const uint4*)(ws + WFRG);

  const int t = threadIdx.x;
  const int lane = t & 63;
  const int w = __builtin_amdgcn_readfirstlane(t >> 6);
  const int mh = w >> 1, nt = w & 1;    // phase-1 roles
  const int oq = w;                     // phase-3 role
  const int b = blockIdx.z;
  const int tY = blockIdx.y * 4, tX = blockIdx.x * 16;
  const unsigned short* upB = upb + (size_t)b * HW * CO;

  union Cvt { uint4 u; short8 s; };

  // ================= phase 1: 3x3 conv over concat(up,low) -> fo_raw ==============
  for (int i = t; i < 16 * 108; i += 256) {
    int px = i >> 4, cg = i & 15;
    int gy = tY - 1 + px / 18, gx = tX - 1 + px % 18;
    uint4 v = make_uint4(0, 0, 0, 0);
    if (gy >= 0 && gy < HO && gx >= 0 && gx < HO) {
      const unsigned short* src =
          (cg < 8 ? upb : lob) + (((size_t)b * HO + gy) * HO + gx) * CO + (cg & 7) * 8;
      v = *(const uint4*)src;
    }
    *(uint4*)&us_in[((size_t)cg * 108 + px) * 8] = v;
  }
  __syncthreads();

  f32x4 acc2[2];
  acc2[0] = {0.f, 0.f, 0.f, 0.f}; acc2[1] = {0.f, 0.f, 0.f, 0.f};
#pragma unroll 1
  for (int tap = 0; tap < 9; ++tap) {
    int ky = tap / 3, kx = tap % 3;
#pragma unroll
    for (int kc = 0; kc < 4; ++kc) {
      Cvt bw; bw.u = wfo[(((size_t)tap * 4 + kc) * 2 + nt) * 64 + lane];
#pragma unroll
      for (int mt = 0; mt < 2; ++mt) {
        int sy = mh * 2 + mt;
        Cvt av;
        av.u = *(const uint4*)&us_in[(((size_t)(kc * 4 + (lane >> 4))) * 108 +
                                      (sy + ky) * 18 + (lane & 15) + kx) * 8];
        acc2[mt] = __builtin_amdgcn_mfma_f32_16x16x32_bf16(av.s, bw.s, acc2[mt], 0, 0, 0);
      }
    }
  }
  __syncthreads();

#pragma unroll
  for (int mt = 0; mt < 2; ++mt)
#pragma unroll
    for (int r = 0; r < 4; ++r)
      fo_raw[(nt * 16 + (lane & 15)) * 66 + mh * 32 + mt * 16 + (lane >> 4) * 4 + r] =
          acc2[mt][r];
  __syncthreads();

  // ================= phase 2: bilinear params from LDS fo ==========================
  for (int i = t; i < 9 * 64; i += 256) {
    int k = i >> 6, px = i & 63;
    int y = tY + (px >> 4), x = tX + (px & 15);
    float offy = fo_raw[(2 * k) * 66 + px] + boff[2 * k];
    float offx = fo_raw[(2 * k + 1) * 66 + px] + boff[2 * k + 1];
    float m = 2.f / (1.f + expf(-(fo_raw[(18 + k) * 66 + px] + boff[18 + k])));
    float pyf = offy + (float)(y - 1 + k / 3);
    float pxf = offx + (float)(x - 1 + k % 3);
    float y0f = floorf(pyf), x0f = floorf(pxf);
    float wy = pyf - y0f, wx = pxf - x0f;
    int y0 = (int)y0f, x0 = (int)x0f;
    int y1 = y0 + 1, x1 = x0 + 1;
    float vy0 = (y0 >= 0 && y0 < HO) ? m : 0.f;
    float vy1 = (y1 >= 0 && y1 < HO) ? m : 0.f;
    float vx0 = (x0 >= 0 && x0 < HO) ? 1.f : 0.f;
    float vx1 = (x1 >= 0 && x1 < HO) ? 1.f : 0.f;
    float* pr = prm + ((size_t)k * 64 + px) * 5;
    pr[0] = (1.f - wy) * (1.f - wx) * vy0 * vx0;
    pr[1] = (1.f - wy) * wx * vy0 * vx1;
    pr[2] = wy * (1.f - wx) * vy1 * vx0;
    pr[3] = wy * wx * vy1 * vx1;
    int cy0 = min(max(y0, 0), HO - 1), cy1 = min(max(y1, 0), HO - 1);
    int cx0 = min(max(x0, 0), HO - 1), cx1 = min(max(x1, 0), HO - 1);
    unsigned pc = (unsigned)cy0 | ((unsigned)cy1 << 8) |
                  ((unsigned)cx0 << 16) | ((unsigned)cx1 << 24);
    pr[4] = __uint_as_float(pc);
  }
  __syncthreads();

  // ================= phase 3: deformable gathers + MFMA GEMM ======================
  uint4 u00[2], u01[2], u10[2], u11[2];

  auto issue = [&](int k) {        // bf16 gathers: 8 lanes x 16B = 128B runs per corner
#pragma unroll
    for (int it = 0; it < 2; ++it) {
      int j = it * 256 + t;
      int q = j & 7, px = j >> 3;
      unsigned pc = __float_as_uint(prm[((size_t)k * 64 + px) * 5 + 4]);
      int cy0 = pc & 255, cy1 = (pc >> 8) & 255, cx0 = (pc >> 16) & 255, cx1 = pc >> 24;
      const unsigned short* base = upB + q * 8;
      u00[it] = *(const uint4*)(base + (size_t)(cy0 * HO + cx0) * CO);
      u01[it] = *(const uint4*)(base + (size_t)(cy0 * HO + cx1) * CO);
      u10[it] = *(const uint4*)(base + (size_t)(cy1 * HO + cx0) * CO);
      u11[it] = *(const uint4*)(base + (size_t)(cy1 * HO + cx1) * CO);
    }
  };

  auto combine = [&](int k, int buf) {
#pragma unroll
    for (int it = 0; it < 2; ++it) {
      int j = it * 256 + t;
      int q = j & 7, px = j >> 3;
      const float* pr = prm + ((size_t)k * 64 + px) * 5;
      float w0 = pr[0], w1 = pr[1], w2 = pr[2], w3 = pr[3];
      unsigned a0[4] = {u00[it].x, u00[it].y, u00[it].z, u00[it].w};
      unsigned a1[4] = {u01[it].x, u01[it].y, u01[it].z, u01[it].w};
      unsigned a2[4] = {u10[it].x, u10[it].y, u10[it].z, u10[it].w};
      unsigned a3[4] = {u11[it].x, u11[it].y, u11[it].z, u11[it].w};
      unsigned rw[4];
#pragma unroll
      for (int p = 0; p < 4; ++p) {
        float l0 = __uint_as_float(a0[p] << 16), h0 = __uint_as_float(a0[p] & 0xffff0000u);
        float l1 = __uint_as_float(a1[p] << 16), h1 = __uint_as_float(a1[p] & 0xffff0000u);
        float l2 = __uint_as_float(a2[p] << 16), h2 = __uint_as_float(a2[p] & 0xffff0000u);
        float l3 = __uint_as_float(a3[p] << 16), h3 = __uint_as_float(a3[p] & 0xffff0000u);
        float vlo = fmaf(w0, l0, fmaf(w1, l1, fmaf(w2, l2, w3 * l3)));
        float vhi = fmaf(w0, h0, fmaf(w1, h1, fmaf(w2, h2, w3 * h3)));
        rw[p] = (unsigned)f2bf(vlo) | ((unsigned)f2bf(vhi) << 16);
      }
      *(uint4*)&us_vt[(((size_t)buf * 8 + q) * 64 + px) * 8] = make_uint4(rw[0], rw[1], rw[2], rw[3]);
    }
  };

  f32x4 acc[4];
#pragma unroll
  for (int mt = 0; mt < 4; ++mt) acc[mt] = {0.f, 0.f, 0.f, 0.f};

  uint4 bw0 = wf[(oq * 18 + 0) * 64 + lane];
  uint4 bw1 = wf[(oq * 18 + 1) * 64 + lane];
  uint4 bn0, bn1;

  issue(0);
  combine(0, 0);
  __syncthreads();

  int buf = 0;
#pragma unroll 1
  for (int k = 0; k < 9; ++k) {
    if (k < 8) {
      issue(k + 1);
      bn0 = wf[(oq * 18 + 2 * k + 2) * 64 + lane];
      bn1 = wf[(oq * 18 + 2 * k + 3) * 64 + lane];
    }
#pragma unroll
    for (int kb2 = 0; kb2 < 2; ++kb2) {
      Cvt bfr; bfr.u = kb2 ? bw1 : bw0;
#pragma unroll
      for (int mt = 0; mt < 4; ++mt) {
        Cvt av;
        av.u = *(const uint4*)&us_vt[(((size_t)buf * 8 + kb2 * 4 + (lane >> 4)) * 64 +
                                      mt * 16 + (lane & 15)) * 8];
        acc[mt] = __builtin_amdgcn_mfma_f32_16x16x32_bf16(av.s, bfr.s, acc[mt], 0, 0, 0);
      }
    }
    if (k < 8) combine(k + 1, buf ^ 1);
    __syncthreads();
    bw0 = bn0; bw1 = bn1;
    buf ^= 1;
  }

  // ================= phase 4: epilogue =============================================
  float* accs = smem;                    // [4][16][65]
#pragma unroll
  for (int mt = 0; mt < 4; ++mt)
#pragma unroll
    for (int r = 0; r < 4; ++r)
      accs[((size_t)oq * 16 + (lane & 15)) * 65 + mt * 16 + (lane >> 4) * 4 + r] = acc[mt][r];
  __syncthreads();

  const int y = tY + (lane >> 4), x = tX + (lane & 15);
  float* ob = out + (size_t)b * 2 * CO * HW + (size_t)y * HO + x;
#pragma unroll
  for (int ol = 0; ol < 16; ++ol) {
    int o = oq * 16 + ol;
    float v = accs[((size_t)oq * 16 + ol) * 65 + lane] + bal[o];
    v = (v >= 0.f) ? v : 0.2f * v;                // leaky relu
    ob[(size_t)o * HW] = v;
  }
}

extern "C" void kernel_launch(void* const* d_in, const int* in_sizes, int n_in,
                              void* d_out, int out_size, void* d_ws, size_t ws_size,
                              hipStream_t stream) {
  const float* high = (const float*)d_in[0];
  const float* low  = (const float*)d_in[1];
  const float* wup  = (const float*)d_in[2];
  const float* bup  = (const float*)d_in[3];
  const float* woff = (const float*)d_in[4];
  const float* boff = (const float*)d_in[5];
  const float* wal  = (const float*)d_in[6];
  const float* bal  = (const float*)d_in[7];
  float* out = (float*)d_out;
  float* ws  = (float*)d_ws;

  k_repack<<<dim3(288), dim3(256), 0, stream>>>(wup, woff, wal, ws);
  k_cvt<<<dim3(HF, B), dim3(256), 0, stream>>>(high, ws);
  k_cvt2<<<dim3(HO, B), dim3(256), 0, stream>>>(low, out, ws);
  k_up<<<dim3(4, 16, B * 4), dim3(256), 0, stream>>>(bup, ws);
  k_offdcn<<<dim3(8, 32, B), dim3(256), 0, stream>>>(boff, bal, out, ws);
}

// Round 8
// 64.226 us; speedup vs baseline: 10.8334x; 1.1099x over previous
//
#include <hip/hip_runtime.h>
#include <math.h>

namespace {
constexpr int B   = 4;
constexpr int CIN = 128;   // high channels
constexpr int CO  = 64;    // up / aligned channels
constexpr int HF  = 64;    // high H=W
constexpr int HO  = 128;   // up/out H=W
constexpr int HW  = HO * HO;   // 16384
constexpr int NOFF = 27;   // 18 offset + 9 mask channels

// workspace layout (float units)
constexpr size_t UPB  = 0;                               // bf16 [B][HO][HO][CO] up, NHWC
constexpr size_t LOB  = UPB + (size_t)B * HW * CO / 2;   // bf16 [B][HO][HO][CO] low, NHWC
constexpr size_t HBF  = LOB + (size_t)B * HW * CO / 2;   // bf16 [B][HF][HF][CIN] high, NHWC
constexpr size_t WFRG = HBF + (size_t)B * HF * HF * CIN / 2;   // k_dcn B-frags [4][18][64][8]
constexpr size_t WFUP = WFRG + (size_t)(4 * 18 * 64 * 8) / 2;  // k_up B-frags [9][4][4][64][8]
constexpr size_t WFOF = WFUP + (size_t)(9 * 4 * 4 * 64 * 8) / 2; // k_off B-frags [9][4][2][64][8]
}

using short8 = __attribute__((ext_vector_type(8))) short;
using f32x4  = __attribute__((ext_vector_type(4))) float;

__device__ __forceinline__ unsigned short f2bf(float f) {
  unsigned u = __float_as_uint(f);
  u += 0x7fffu + ((u >> 16) & 1u);      // RNE
  return (unsigned short)(u >> 16);
}

// ---------------- K0: fused prep — weight repack + high/low NCHW->bf16 NHWC -------
// blocks [0,288): repack; [288,544): high cvt; [544,1056): low cvt + out copy.
__global__ __launch_bounds__(256) void k_prep(const float* __restrict__ high,
                                              const float* __restrict__ low,
                                              const float* __restrict__ wup,
                                              const float* __restrict__ woff,
                                              const float* __restrict__ wal,
                                              float* __restrict__ out,
                                              float* __restrict__ ws) {
  __shared__ unsigned short tl[64][130];     // 16640 B, shared by both cvt paths
  const int bid = blockIdx.x;
  const int t = threadIdx.x;

  if (bid < 288) {                           // ---- weight repack ----
    int i = bid * 256 + t;
    if (i < 4 * 18 * 64 * 8) {               // k_dcn: [w][kb][lane][j]
      int j = i & 7; int t2 = i >> 3;
      int lane = t2 & 63; int t3 = t2 >> 6;
      int kb = t3 % 18; int w = t3 / 18;
      int tap = kb >> 1;
      int c = (kb & 1) * 32 + ((lane >> 4) << 3) + j;
      int o = (w << 4) + (lane & 15);
      unsigned short* wfrag = (unsigned short*)(ws + WFRG);
      wfrag[i] = f2bf(wal[((size_t)o * CO + c) * 9 + tap]);
    }
    if (i < 9 * 4 * 4 * 64 * 8) {            // k_up: [rr][ch][w][lane][j]
      int j = i & 7; int lane = (i >> 3) & 63; int w = (i >> 9) & 3;
      int ch = (i >> 11) & 3; int rr = i >> 13;
      int c = ch * 32 + ((lane >> 4) << 3) + j;
      int o = w * 16 + (lane & 15);
      unsigned short* wfup = (unsigned short*)(ws + WFUP);
      wfup[i] = f2bf(wup[((size_t)c * CO + o) * 9 + rr]);
    }
    if (i < 9 * 4 * 2 * 64 * 8) {            // k_off: [tap][kc][nt][lane][j]
      int j = i & 7; int lane = (i >> 3) & 63; int nt = (i >> 9) & 1;
      int kc = (i >> 10) & 3; int tap = i >> 12;
      int c = kc * 32 + ((lane >> 4) << 3) + j;
      int o = nt * 16 + (lane & 15);
      float v = 0.f;
      if (o < NOFF) v = woff[(((size_t)o * 2 * CO + c) * 3 + tap / 3) * 3 + (tap % 3)];
      unsigned short* wfo = (unsigned short*)(ws + WFOF);
      wfo[i] = f2bf(v);
    }
    return;
  }

  if (bid < 544) {                           // ---- high fp32 NCHW -> bf16 NHWC ----
    unsigned short (*tl2)[66] = (unsigned short(*)[66])&tl[0][0];
    unsigned short* hbf = (unsigned short*)(ws + HBF);
    int j = bid - 288;
    const int y = j & 63, b = j >> 6;
    const int x = t & 63, clb = t >> 6;
    for (int c0 = 0; c0 < CIN; c0 += 32) {
      __syncthreads();
#pragma unroll
      for (int k = 0; k < 8; ++k) {
        int cl = clb * 8 + k;
        float v = high[(((size_t)b * CIN + c0 + cl) * HF + y) * HF + x];
        tl2[cl][x] = f2bf(v);
      }
      __syncthreads();
      int px = t >> 2, cg = t & 3;
      ushort4 a, bb;
      a.x = tl2[cg * 8 + 0][px]; a.y = tl2[cg * 8 + 1][px];
      a.z = tl2[cg * 8 + 2][px]; a.w = tl2[cg * 8 + 3][px];
      bb.x = tl2[cg * 8 + 4][px]; bb.y = tl2[cg * 8 + 5][px];
      bb.z = tl2[cg * 8 + 6][px]; bb.w = tl2[cg * 8 + 7][px];
      unsigned short* dst = hbf + (((size_t)b * HF + y) * HF + px) * CIN + c0 + cg * 8;
      *(ushort4*)(dst) = a;
      *(ushort4*)(dst + 4) = bb;
    }
    return;
  }

  {                                          // ---- low -> bf16 NHWC + fp32 out copy ----
    unsigned short* lob = (unsigned short*)(ws + LOB);
    int j = bid - 544;
    const int y = j & 127, b = j >> 7;
#pragma unroll
    for (int it = 0; it < 8; ++it) {         // 2048 float4 over 256 threads
      int i = it * 256 + t;
      int c = i >> 5, xi = (i & 31) * 4;
      float4 v = *(const float4*)(low + (((size_t)b * CO + c) * HO + y) * HO + xi);
      *(float4*)(out + (((size_t)b * 2 * CO + CO + c) * HO + y) * HO + xi) = v;
      tl[c][xi + 0] = f2bf(v.x); tl[c][xi + 1] = f2bf(v.y);
      tl[c][xi + 2] = f2bf(v.z); tl[c][xi + 3] = f2bf(v.w);
    }
    __syncthreads();
#pragma unroll
    for (int it = 0; it < 4; ++it) {         // 128 px x 8 cgroups
      int i = it * 256 + t;
      int x = i >> 3, cg = i & 7;
      unsigned rw[4];
#pragma unroll
      for (int p = 0; p < 4; ++p)
        rw[p] = (unsigned)tl[cg * 8 + 2 * p][x] | ((unsigned)tl[cg * 8 + 2 * p + 1][x] << 16);
      *(uint4*)(lob + (((size_t)b * HO + y) * HO + x) * CO + cg * 8) =
          make_uint4(rw[0], rw[1], rw[2], rw[3]);
    }
  }
}

// ---------------- K1: transposed conv as per-parity MFMA GEMM, bf16 NHWC out ------
// 1D grid 1024, XCD-swizzled; parity fastest (4 parity blocks share staging via L2).
union SmemUp {
  unsigned short At[2][4][85][8];       // [buf][cg][5*17 px][8ch] bf16
  float accs[4][16][65];                // epilogue transpose (pad 65)
};

__global__ __launch_bounds__(256) void k_up(const float* __restrict__ bup,
                                            float* __restrict__ ws) {
  __shared__ SmemUp sm;
  const unsigned short* hbf = (const unsigned short*)(ws + HBF);
  const uint4* wfu = (const uint4*)(ws + WFUP);
  unsigned short* upb = (unsigned short*)(ws + UPB);

  const int t    = threadIdx.x;
  const int lane = t & 63;
  const int oq   = __builtin_amdgcn_readfirstlane(t >> 6);
  const int orig = blockIdx.x;
  const int tile = ((orig & 7) << 7) + (orig >> 3);   // XCD swizzle (1024 = 8*128)
  const int par  = tile & 3;
  const int pyv  = (par >> 1) & 1, pxv = par & 1;
  const int tx   = ((tile >> 2) & 3) * 16;
  const int ty   = ((tile >> 4) & 15) * 4;
  const int b    = tile >> 8;
  const int nty  = pyv + 1, ntx = pxv + 1;

  uint4 s0, s1;
  const int pxA = t >> 2, cgA = t & 3;
  const int i2 = t + 256, pxB = i2 >> 2, cgB = i2 & 3;

  auto load_chunk = [&](int c0) {
    {
      int gy = ty + pxA / 17, gx = tx + pxA % 17;
      s0 = make_uint4(0, 0, 0, 0);
      if (gy < HF && gx < HF)
        s0 = *(const uint4*)(hbf + (((size_t)b * HF + gy) * HF + gx) * CIN + c0 + cgA * 8);
    }
    s1 = make_uint4(0, 0, 0, 0);
    if (pxB < 85) {
      int gy = ty + pxB / 17, gx = tx + pxB % 17;
      if (gy < HF && gx < HF)
        s1 = *(const uint4*)(hbf + (((size_t)b * HF + gy) * HF + gx) * CIN + c0 + cgB * 8);
    }
  };
  auto write_chunk = [&](int buf) {
    *(uint4*)&sm.At[buf][cgA][pxA][0] = s0;
    if (pxB < 85) *(uint4*)&sm.At[buf][cgB][pxB][0] = s1;
  };

  f32x4 acc[4];
#pragma unroll
  for (int mt = 0; mt < 4; ++mt) acc[mt] = {0.f, 0.f, 0.f, 0.f};

  load_chunk(0);
  write_chunk(0);
  __syncthreads();

  union Cvt { uint4 u; short8 s; };
  int buf = 0;
#pragma unroll 1
  for (int ch = 0; ch < 4; ++ch) {
    if (ch < 3) load_chunk((ch + 1) * 32);
#pragma unroll
    for (int ti = 0; ti < 2; ++ti) {
      if (ti < nty) {
#pragma unroll
        for (int tj = 0; tj < 2; ++tj) {
          if (tj < ntx) {
            int ryA = pyv ? 2 - 2 * ti : 1;
            int rxA = pxv ? 2 - 2 * tj : 1;
            int rr = ryA * 3 + rxA;
            Cvt bw; bw.u = wfu[(((size_t)rr * 4 + ch) * 4 + oq) * 64 + lane];
#pragma unroll
            for (int mt = 0; mt < 4; ++mt) {
              Cvt av;
              av.u = *(const uint4*)&sm.At[buf][lane >> 4][(mt + ti) * 17 + (lane & 15) + tj][0];
              acc[mt] = __builtin_amdgcn_mfma_f32_16x16x32_bf16(av.s, bw.s, acc[mt], 0, 0, 0);
            }
          }
        }
      }
    }
    if (ch < 3) write_chunk(buf ^ 1);
    __syncthreads();
    buf ^= 1;
  }

  // epilogue: transpose via padded LDS, bf16 NHWC stores + bias
#pragma unroll
  for (int mt = 0; mt < 4; ++mt)
#pragma unroll
    for (int r = 0; r < 4; ++r)
      sm.accs[oq][lane & 15][mt * 16 + (lane >> 4) * 4 + r] = acc[mt][r];
  __syncthreads();

  const int yo = 2 * (ty + (lane >> 4)) + pyv;
  const int xo = 2 * (tx + (lane & 15)) + pxv;
  unsigned short* dst = upb + (((size_t)b * HO + yo) * HO + xo) * CO + oq * 16;
  unsigned rw[8];
#pragma unroll
  for (int p = 0; p < 8; ++p) {
    float v0 = sm.accs[oq][2 * p][lane] + bup[oq * 16 + 2 * p];
    float v1 = sm.accs[oq][2 * p + 1][lane] + bup[oq * 16 + 2 * p + 1];
    rw[p] = (unsigned)f2bf(v0) | ((unsigned)f2bf(v1) << 16);
  }
  *(uint4*)dst = make_uint4(rw[0], rw[1], rw[2], rw[3]);
  *(uint4*)(dst + 8) = make_uint4(rw[4], rw[5], rw[6], rw[7]);
}

// ---------------- K2: FUSED offset-conv (MFMA) + modulated deformable conv --------
// Tile 64 px (16x4), 1D grid 1024 XCD-swizzled. fo never leaves LDS.
// LDS arena 31744 B (5 blocks/CU), phase-overlaid:
//   phase1: in[16][108][8] bf16 @0 (27648 B)
//   phase2: fo_raw[32][66] f32 @0 (8448) + prm u32 [9][64][3] @8448 (6912, bf16-packed w)
//   phase3: prm (kept) + Vt[2][8][64][8] bf16 @15360 (16384)
//   phase4: accs[4][16][65] f32 @0 (16640)
__global__ __launch_bounds__(256) void k_offdcn(const float* __restrict__ boff,
                                                const float* __restrict__ bal,
                                                float* __restrict__ out,
                                                const float* __restrict__ ws) {
  __shared__ float smem[7936];          // 31744 B
  unsigned short* us_in = (unsigned short*)smem;
  float* fo_raw = smem;                                    // [32][66]
  unsigned* prm = (unsigned*)(smem + 2112);                // [9][64][3]
  unsigned short* us_vt = (unsigned short*)(smem + 3840);  // [2][8][64][8]

  const unsigned short* upb = (const unsigned short*)(ws + UPB);
  const unsigned short* lob = (const unsigned short*)(ws + LOB);
  const uint4* wfo = (const uint4*)(ws + WFOF);
  const uint4* wf  = (const uint4*)(ws + WFRG);

  const int t = threadIdx.x;
  const int lane = t & 63;
  const int w = __builtin_amdgcn_readfirstlane(t >> 6);
  const int mh = w >> 1, nt = w & 1;    // phase-1 roles
  const int oq = w;                     // phase-3 role
  const int orig = blockIdx.x;
  const int tile = ((orig & 7) << 7) + (orig >> 3);   // XCD swizzle (1024 = 8*128)
  const int tX = (tile & 7) * 16;
  const int tY = ((tile >> 3) & 31) * 4;
  const int b  = tile >> 8;
  const unsigned short* upB = upb + (size_t)b * HW * CO;

  union Cvt { uint4 u; short8 s; };

  // ================= phase 1: 3x3 conv over concat(up,low) -> fo_raw ==============
  for (int i = t; i < 16 * 108; i += 256) {
    int px = i >> 4, cg = i & 15;
    int gy = tY - 1 + px / 18, gx = tX - 1 + px % 18;
    uint4 v = make_uint4(0, 0, 0, 0);
    if (gy >= 0 && gy < HO && gx >= 0 && gx < HO) {
      const unsigned short* src =
          (cg < 8 ? upb : lob) + (((size_t)b * HO + gy) * HO + gx) * CO + (cg & 7) * 8;
      v = *(const uint4*)src;
    }
    *(uint4*)&us_in[((size_t)cg * 108 + px) * 8] = v;
  }
  __syncthreads();

  f32x4 acc2[2];
  acc2[0] = {0.f, 0.f, 0.f, 0.f}; acc2[1] = {0.f, 0.f, 0.f, 0.f};
#pragma unroll 1
  for (int tap = 0; tap < 9; ++tap) {
    int ky = tap / 3, kx = tap % 3;
#pragma unroll
    for (int kc = 0; kc < 4; ++kc) {
      Cvt bw; bw.u = wfo[(((size_t)tap * 4 + kc) * 2 + nt) * 64 + lane];
#pragma unroll
      for (int mt = 0; mt < 2; ++mt) {
        int sy = mh * 2 + mt;
        Cvt av;
        av.u = *(const uint4*)&us_in[(((size_t)(kc * 4 + (lane >> 4))) * 108 +
                                      (sy + ky) * 18 + (lane & 15) + kx) * 8];
        acc2[mt] = __builtin_amdgcn_mfma_f32_16x16x32_bf16(av.s, bw.s, acc2[mt], 0, 0, 0);
      }
    }
  }
  __syncthreads();

#pragma unroll
  for (int mt = 0; mt < 2; ++mt)
#pragma unroll
    for (int r = 0; r < 4; ++r)
      fo_raw[(nt * 16 + (lane & 15)) * 66 + mh * 32 + mt * 16 + (lane >> 4) * 4 + r] =
          acc2[mt][r];
  __syncthreads();

  // ================= phase 2: bilinear params from LDS fo ==========================
  for (int i = t; i < 9 * 64; i += 256) {
    int k = i >> 6, px = i & 63;
    int y = tY + (px >> 4), x = tX + (px & 15);
    float offy = fo_raw[(2 * k) * 66 + px] + boff[2 * k];
    float offx = fo_raw[(2 * k + 1) * 66 + px] + boff[2 * k + 1];
    float m = 2.f / (1.f + expf(-(fo_raw[(18 + k) * 66 + px] + boff[18 + k])));
    float pyf = offy + (float)(y - 1 + k / 3);
    float pxf = offx + (float)(x - 1 + k % 3);
    float y0f = floorf(pyf), x0f = floorf(pxf);
    float wy = pyf - y0f, wx = pxf - x0f;
    int y0 = (int)y0f, x0 = (int)x0f;
    int y1 = y0 + 1, x1 = x0 + 1;
    float vy0 = (y0 >= 0 && y0 < HO) ? m : 0.f;
    float vy1 = (y1 >= 0 && y1 < HO) ? m : 0.f;
    float vx0 = (x0 >= 0 && x0 < HO) ? 1.f : 0.f;
    float vx1 = (x1 >= 0 && x1 < HO) ? 1.f : 0.f;
    float w0 = (1.f - wy) * (1.f - wx) * vy0 * vx0;
    float w1 = (1.f - wy) * wx * vy0 * vx1;
    float w2 = wy * (1.f - wx) * vy1 * vx0;
    float w3 = wy * wx * vy1 * vx1;
    int cy0 = min(max(y0, 0), HO - 1), cy1 = min(max(y1, 0), HO - 1);
    int cx0 = min(max(x0, 0), HO - 1), cx1 = min(max(x1, 0), HO - 1);
    unsigned pc = (unsigned)cy0 | ((unsigned)cy1 << 8) |
                  ((unsigned)cx0 << 16) | ((unsigned)cx1 << 24);
    unsigned* pr = prm + ((size_t)k * 64 + px) * 3;
    pr[0] = (unsigned)f2bf(w0) | ((unsigned)f2bf(w1) << 16);
    pr[1] = (unsigned)f2bf(w2) | ((unsigned)f2bf(w3) << 16);
    pr[2] = pc;
  }
  __syncthreads();

  // ================= phase 3: deformable gathers + MFMA GEMM ======================
  uint4 u00[2], u01[2], u10[2], u11[2];

  auto issue = [&](int k) {        // bf16 gathers: 8 lanes x 16B = 128B runs per corner
#pragma unroll
    for (int it = 0; it < 2; ++it) {
      int j = it * 256 + t;
      int q = j & 7, px = j >> 3;
      unsigned pc = prm[((size_t)k * 64 + px) * 3 + 2];
      int cy0 = pc & 255, cy1 = (pc >> 8) & 255, cx0 = (pc >> 16) & 255, cx1 = pc >> 24;
      const unsigned short* base = upB + q * 8;
      u00[it] = *(const uint4*)(base + (size_t)(cy0 * HO + cx0) * CO);
      u01[it] = *(const uint4*)(base + (size_t)(cy0 * HO + cx1) * CO);
      u10[it] = *(const uint4*)(base + (size_t)(cy1 * HO + cx0) * CO);
      u11[it] = *(const uint4*)(base + (size_t)(cy1 * HO + cx1) * CO);
    }
  };

  auto combine = [&](int k, int buf) {
#pragma unroll
    for (int it = 0; it < 2; ++it) {
      int j = it * 256 + t;
      int q = j & 7, px = j >> 3;
      const unsigned* pr = prm + ((size_t)k * 64 + px) * 3;
      unsigned pw01 = pr[0], pw23 = pr[1];
      float w0 = __uint_as_float(pw01 << 16), w1 = __uint_as_float(pw01 & 0xffff0000u);
      float w2 = __uint_as_float(pw23 << 16), w3 = __uint_as_float(pw23 & 0xffff0000u);
      unsigned a0[4] = {u00[it].x, u00[it].y, u00[it].z, u00[it].w};
      unsigned a1[4] = {u01[it].x, u01[it].y, u01[it].z, u01[it].w};
      unsigned a2[4] = {u10[it].x, u10[it].y, u10[it].z, u10[it].w};
      unsigned a3[4] = {u11[it].x, u11[it].y, u11[it].z, u11[it].w};
      unsigned rw[4];
#pragma unroll
      for (int p = 0; p < 4; ++p) {
        float l0 = __uint_as_float(a0[p] << 16), h0 = __uint_as_float(a0[p] & 0xffff0000u);
        float l1 = __uint_as_float(a1[p] << 16), h1 = __uint_as_float(a1[p] & 0xffff0000u);
        float l2 = __uint_as_float(a2[p] << 16), h2 = __uint_as_float(a2[p] & 0xffff0000u);
        float l3 = __uint_as_float(a3[p] << 16), h3 = __uint_as_float(a3[p] & 0xffff0000u);
        float vlo = fmaf(w0, l0, fmaf(w1, l1, fmaf(w2, l2, w3 * l3)));
        float vhi = fmaf(w0, h0, fmaf(w1, h1, fmaf(w2, h2, w3 * h3)));
        rw[p] = (unsigned)f2bf(vlo) | ((unsigned)f2bf(vhi) << 16);
      }
      *(uint4*)&us_vt[(((size_t)buf * 8 + q) * 64 + px) * 8] = make_uint4(rw[0], rw[1], rw[2], rw[3]);
    }
  };

  f32x4 acc[4];
#pragma unroll
  for (int mt = 0; mt < 4; ++mt) acc[mt] = {0.f, 0.f, 0.f, 0.f};

  uint4 bw0 = wf[(oq * 18 + 0) * 64 + lane];
  uint4 bw1 = wf[(oq * 18 + 1) * 64 + lane];
  uint4 bn0, bn1;

  issue(0);
  combine(0, 0);
  __syncthreads();

  int buf = 0;
#pragma unroll 1
  for (int k = 0; k < 9; ++k) {
    if (k < 8) {
      issue(k + 1);
      bn0 = wf[(oq * 18 + 2 * k + 2) * 64 + lane];
      bn1 = wf[(oq * 18 + 2 * k + 3) * 64 + lane];
    }
#pragma unroll
    for (int kb2 = 0; kb2 < 2; ++kb2) {
      Cvt bfr; bfr.u = kb2 ? bw1 : bw0;
#pragma unroll
      for (int mt = 0; mt < 4; ++mt) {
        Cvt av;
        av.u = *(const uint4*)&us_vt[(((size_t)buf * 8 + kb2 * 4 + (lane >> 4)) * 64 +
                                      mt * 16 + (lane & 15)) * 8];
        acc[mt] = __builtin_amdgcn_mfma_f32_16x16x32_bf16(av.s, bfr.s, acc[mt], 0, 0, 0);
      }
    }
    if (k < 8) combine(k + 1, buf ^ 1);
    __syncthreads();
    bw0 = bn0; bw1 = bn1;
    buf ^= 1;
  }

  // ================= phase 4: epilogue =============================================
  float* accs = smem;                    // [4][16][65]
#pragma unroll
  for (int mt = 0; mt < 4; ++mt)
#pragma unroll
    for (int r = 0; r < 4; ++r)
      accs[((size_t)oq * 16 + (lane & 15)) * 65 + mt * 16 + (lane >> 4) * 4 + r] = acc[mt][r];
  __syncthreads();

  const int y = tY + (lane >> 4), x = tX + (lane & 15);
  float* ob = out + (size_t)b * 2 * CO * HW + (size_t)y * HO + x;
#pragma unroll
  for (int ol = 0; ol < 16; ++ol) {
    int o = oq * 16 + ol;
    float v = accs[((size_t)oq * 16 + ol) * 65 + lane] + bal[o];
    v = (v >= 0.f) ? v : 0.2f * v;                // leaky relu
    ob[(size_t)o * HW] = v;
  }
}

extern "C" void kernel_launch(void* const* d_in, const int* in_sizes, int n_in,
                              void* d_out, int out_size, void* d_ws, size_t ws_size,
                              hipStream_t stream) {
  const float* high = (const float*)d_in[0];
  const float* low  = (const float*)d_in[1];
  const float* wup  = (const float*)d_in[2];
  const float* bup  = (const float*)d_in[3];
  const float* woff = (const float*)d_in[4];
  const float* boff = (const float*)d_in[5];
  const float* wal  = (const float*)d_in[6];
  const float* bal  = (const float*)d_in[7];
  float* out = (float*)d_out;
  float* ws  = (float*)d_ws;

  k_prep<<<dim3(1056), dim3(256), 0, stream>>>(high, low, wup, woff, wal, out, ws);
  k_up<<<dim3(1024), dim3(256), 0, stream>>>(bup, ws);
  k_offdcn<<<dim3(1024), dim3(256), 0, stream>>>(boff, bal, out, ws);
}